// Round 11
// baseline (230.636 us; speedup 1.0000x reference)
//
#include <hip/hip_runtime.h>
#include <hip/hip_bf16.h>

#define EMB 768
#define HEADS 12
#define DKV 64
#define BATCH 2
#define SEQ 2048
#define NTOK (BATCH*SEQ)   // 4096

typedef float f32x4 __attribute__((ext_vector_type(4)));
typedef unsigned short u16;
typedef u16 u16x8 __attribute__((ext_vector_type(8)));
typedef u16 u16x4 __attribute__((ext_vector_type(4)));
typedef __bf16 bf16x8 __attribute__((ext_vector_type(8)));

__device__ __forceinline__ u16 f2bf(float f) {
  return __builtin_bit_cast(u16, (__bf16)f);
}
__device__ __forceinline__ float fexp2(float x) {
#if __has_builtin(__builtin_amdgcn_exp2f)
  return __builtin_amdgcn_exp2f(x);
#else
  return exp2f(x);
#endif
}
__device__ __forceinline__ f32x4 mfma16(u16x8 a, u16x8 b, f32x4 c) {
  return __builtin_amdgcn_mfma_f32_16x16x32_bf16(
      __builtin_bit_cast(bf16x8, a), __builtin_bit_cast(bf16x8, b), c, 0, 0, 0);
}
// async global->LDS, 16B/lane; LDS dest must be wave-uniform base + lane*16
__device__ __forceinline__ void gload16(const void* g, void* l) {
  __builtin_amdgcn_global_load_lds(
      (const __attribute__((address_space(1))) void*)g,
      (__attribute__((address_space(3))) void*)l, 16, 0, 0);
}

// ---------------- fused cast pass: 3 x's + 4 W's fp32 -> bf16 ----------------
__global__ void cast_all_k(
    const float* __restrict__ x0, const float* __restrict__ x1, const float* __restrict__ x2,
    const float* __restrict__ w0, const float* __restrict__ w1,
    const float* __restrict__ w2, const float* __restrict__ w3,
    u16* __restrict__ X0, u16* __restrict__ X1, u16* __restrict__ X2,
    u16* __restrict__ W0, u16* __restrict__ W1, u16* __restrict__ W2, u16* __restrict__ W3,
    float wscale0)
{
  const int NX = NTOK*EMB/8;   // 393216
  const int NW = EMB*EMB/8;    // 73728
  const int total = 3*NX + 4*NW;
  int i = blockIdx.x*256 + threadIdx.x;
  for (; i < total; i += gridDim.x*256) {
    const float* s; u16* d; int off; float sc = 1.f;
    if (i < 3*NX) {
      int which = i / NX; off = i - which*NX;
      s = which==0 ? x0 : which==1 ? x1 : x2;
      d = which==0 ? X0 : which==1 ? X1 : X2;
    } else {
      int j = i - 3*NX; int which = j / NW; off = j - which*NW;
      s = which==0 ? w0 : which==1 ? w1 : which==2 ? w2 : w3;
      d = which==0 ? W0 : which==1 ? W1 : which==2 ? W2 : W3;
      if (which == 0) sc = wscale0;
    }
    float4 a = reinterpret_cast<const float4*>(s)[off*2];
    float4 b = reinterpret_cast<const float4*>(s)[off*2+1];
    u16x8 o;
    o[0]=f2bf(a.x*sc); o[1]=f2bf(a.y*sc); o[2]=f2bf(a.z*sc); o[3]=f2bf(a.w*sc);
    o[4]=f2bf(b.x*sc); o[5]=f2bf(b.y*sc); o[6]=f2bf(b.z*sc); o[7]=f2bf(b.w*sc);
    reinterpret_cast<u16x8*>(d)[off] = o;
  }
}

// ---------------- GEMM core, m97 structure (unchanged from round 9) ----------------
template<int MODE>
__device__ __forceinline__ void gemm_core(
    const u16* __restrict__ A, const u16* __restrict__ Bm,
    const float* __restrict__ bias, float bscale, void* __restrict__ outp,
    u16* __restrict__ At, u16* __restrict__ Bt, int m0, int n0)
{
  const int t = threadIdx.x;
  const int w = t >> 6, lane = t & 63, lg = lane >> 4, lr = lane & 15;
  const int wr = w >> 1, wc = w & 1;

  f32x4 acc[4][4] = {};

  const int crow = (w*4)*8 + (lane >> 3);
  const int csl  = lane & 7;

  auto STAGE = [&](int kb) {
    #pragma unroll
    for (int i = 0; i < 4; ++i) {
      int row = crow + i*8;
      int sg = csl ^ (row & 7);
      gload16(A  + (size_t)(m0+row)*EMB + kb + sg*8, &At[(w*4+i)*512]);
      gload16(Bm + (size_t)(n0+row)*EMB + kb + sg*8, &Bt[(w*4+i)*512]);
    }
  };

  auto COMPUTE = [&]() {
    u16x8 af[4][2], bf[4][2];
    #pragma unroll
    for (int fm = 0; fm < 4; ++fm)
      #pragma unroll
      for (int kk = 0; kk < 2; ++kk) {
        int r = wr*64 + fm*16 + lr;
        int p = (lg + 4*kk) ^ (r & 7);
        af[fm][kk] = *reinterpret_cast<const u16x8*>(&At[r*64 + p*8]);
      }
    #pragma unroll
    for (int fn = 0; fn < 4; ++fn)
      #pragma unroll
      for (int kk = 0; kk < 2; ++kk) {
        int r = wc*64 + fn*16 + lr;
        int p = (lg + 4*kk) ^ (r & 7);
        bf[fn][kk] = *reinterpret_cast<const u16x8*>(&Bt[r*64 + p*8]);
      }
    __builtin_amdgcn_s_setprio(1);
    #pragma unroll
    for (int fm = 0; fm < 4; ++fm)
      #pragma unroll
      for (int fn = 0; fn < 4; ++fn)
        #pragma unroll
        for (int kk = 0; kk < 2; ++kk)
          acc[fm][fn] = mfma16(af[fm][kk], bf[fn][kk], acc[fm][fn]);
    __builtin_amdgcn_s_setprio(0);
  };

  const int NSTEP = EMB/64;   // 12
  #pragma unroll
  for (int ts = 0; ts < NSTEP; ++ts) {
    STAGE(ts*64);
    __syncthreads();
    COMPUTE();
    if (ts+1 < NSTEP) __syncthreads();
  }

  #pragma unroll
  for (int fm = 0; fm < 4; ++fm)
    #pragma unroll
    for (int fn = 0; fn < 4; ++fn) {
      const int mb = m0 + wr*64 + fm*16 + lg*4;
      const int e  = n0 + wc*64 + fn*16 + lr;
      if constexpr (MODE == 2) {
        int bb = mb >> 11, sb = mb & 2047, h = e >> 6, d = e & 63;
        u16x4 o4;
        #pragma unroll
        for (int j = 0; j < 4; ++j) o4[j] = f2bf(acc[fm][fn][j] + bias[e]*bscale);
        *reinterpret_cast<u16x4*>(
            reinterpret_cast<u16*>(outp) + (((size_t)(bb*HEADS+h))*DKV + d)*SEQ + sb) = o4;
      } else {
        #pragma unroll
        for (int j = 0; j < 4; ++j) {
          int m = mb + j;
          float val = acc[fm][fn][j] + bias[e]*bscale;
          if constexpr (MODE == 0) {
            int bb = m >> 11, s = m & 2047, h = e >> 6, d = e & 63;
            reinterpret_cast<u16*>(outp)[(((size_t)(bb*HEADS+h))*SEQ + s)*DKV + d] = f2bf(val);
          } else {
            reinterpret_cast<float*>(outp)[(size_t)m*EMB + e] = val;
          }
        }
      }
    }
}

__global__ __launch_bounds__(256) void qkv_k(
    const u16* __restrict__ Xq, const u16* __restrict__ Xk, const u16* __restrict__ Xv,
    const u16* __restrict__ Wq, const u16* __restrict__ Wk, const u16* __restrict__ Wv,
    const float* __restrict__ bq, const float* __restrict__ bk, const float* __restrict__ bv,
    u16* __restrict__ Qh, u16* __restrict__ Kh, u16* __restrict__ Vh, float csc)
{
  __shared__ __align__(16) u16 At[128*64];
  __shared__ __align__(16) u16 Bt[128*64];
  const int m0 = blockIdx.x*128, n0 = blockIdx.y*128;
  const int z = blockIdx.z;
  if (z == 0)
    gemm_core<0>(Xq, Wq, bq, csc, Qh, At, Bt, m0, n0);
  else if (z == 1)
    gemm_core<0>(Xk, Wk, bk, 1.f, Kh, At, Bt, m0, n0);
  else
    gemm_core<2>(Xv, Wv, bv, 1.f, Vh, At, Bt, m0, n0);
}

__global__ __launch_bounds__(256) void gemm_out_k(
    const u16* __restrict__ A, const u16* __restrict__ Bm,
    const float* __restrict__ bias, float* __restrict__ outp)
{
  __shared__ __align__(16) u16 At[128*64];
  __shared__ __align__(16) u16 Bt[128*64];
  gemm_core<1>(A, Bm, bias, 1.f, outp, At, Bt, blockIdx.x*128, blockIdx.y*128);
}

// ---------------- flash attention: cache-direct K/V, LDS only for P ----------------
// 16x16 swapped structure (r7-verified): S^T = mfma(K,Q), lane owns q=lr,
// per-lane softmax, defer-max THR=8, partial lrun. K and V fragments are
// IDENTICAL across the 4 waves and K/V is 512 KB/bh -> read them DIRECTLY from
// global (L1 serves 3/4 waves, L2 the rest; common-mistake #7: don't stage what
// caches fit). LDS holds only the per-wave P tile (4 KB round-trip, same-wave
// lgkmcnt fence). NO __syncthreads in the loop. XCD-aware block-id decode puts
// all 32 q-blocks of one bh on one XCD (K/V L2-resident there).
__global__ __launch_bounds__(256) void flash_attn_k(
    const u16* __restrict__ Q, const u16* __restrict__ K, const u16* __restrict__ VT,
    u16* __restrict__ av)
{
  __shared__ __align__(16) u16 Pt[4][16*64];   // per-wave [q][k] swizzled

  const int t = threadIdx.x;
  const int w = t >> 6, lane = t & 63, lg = lane >> 4, lr = lane & 15;
  // XCD decode: round-robin dispatch -> XCD ~= id%8; give each XCD whole bh's.
  const int id = blockIdx.x;                 // 0..767
  const int bh = (id & 7) + 8*(id >> 8);     // 0..23
  const int qb = (id >> 3) & 31;             // 0..31
  const u16* Qb = Q  + (size_t)bh*SEQ*DKV;
  const u16* Kb = K  + (size_t)bh*SEQ*DKV;
  const u16* Vb = VT + (size_t)bh*DKV*SEQ;

  const int qrow = qb*64 + w*16 + lr;
  u16x8 qf[2];
  qf[0] = *reinterpret_cast<const u16x8*>(Qb + (size_t)qrow*DKV + lg*8);
  qf[1] = *reinterpret_cast<const u16x8*>(Qb + (size_t)qrow*DKV + 32 + lg*8);

  // hoisted fragment bases
  const u16* kbase = Kb + (size_t)lr*DKV + lg*8;   // + kt0*DKV + fc*16*DKV + kk*32
  const u16* vbase = Vb + (size_t)lr*SEQ + lg*8;   // + fc*16*SEQ + kt0 + kk*32

  f32x4 acc[4] = {};   // O^T: acc[fc][j] -> d = fc*16+lg*4+j, q = lr
  float mrun = -1e30f, lrun = 0.f;   // lrun = per-lane PARTIAL (16 keys/tile)
  char* Pw = reinterpret_cast<char*>(&Pt[w][0]);

  for (int kt0 = 0; kt0 < SEQ; kt0 += 64) {
    // QK^T: fragments straight from global (L1/L2)
    f32x4 s[4];
    __builtin_amdgcn_s_setprio(1);
    #pragma unroll
    for (int fc = 0; fc < 4; ++fc) {
      f32x4 z = {};
      #pragma unroll
      for (int kk = 0; kk < 2; ++kk) {
        u16x8 kf = *reinterpret_cast<const u16x8*>(
            kbase + (size_t)(kt0 + fc*16)*DKV + kk*32);
        z = mfma16(kf, qf[kk], z);
      }
      s[fc] = z;
    }
    __builtin_amdgcn_s_setprio(0);

    // per-lane online softmax (lane owns q=lr; 16 of 64 keys local)
    float a0 = fmaxf(fmaxf(s[0][0], s[0][1]), s[0][2]);
    float a1 = fmaxf(fmaxf(s[0][3], s[1][0]), s[1][1]);
    float a2 = fmaxf(fmaxf(s[1][2], s[1][3]), s[2][0]);
    float a3 = fmaxf(fmaxf(s[2][1], s[2][2]), s[2][3]);
    float a4 = fmaxf(fmaxf(s[3][0], s[3][1]), s[3][2]);
    float pmax = fmaxf(fmaxf(fmaxf(a0, a1), a2),
                       fmaxf(fmaxf(a3, a4), s[3][3]));
    if (__any(pmax > mrun + 8.f)) {   // rare: full reduce + rescale (T13)
      float pm = fmaxf(pmax, __shfl_xor(pmax, 16));
      pm = fmaxf(pm, __shfl_xor(pm, 32));
      float mnew = fmaxf(mrun, pm);
      float corr = fexp2(mrun - mnew);
      mrun = mnew; lrun *= corr;
      #pragma unroll
      for (int fc = 0; fc < 4; ++fc)
        #pragma unroll
        for (int j = 0; j < 4; ++j)
          acc[fc][j] *= corr;
    }
    float p[4][4], rsv[4];
    #pragma unroll
    for (int fc = 0; fc < 4; ++fc) {
      #pragma unroll
      for (int j = 0; j < 4; ++j) p[fc][j] = fexp2(s[fc][j] - mrun);
      rsv[fc] = (p[fc][0] + p[fc][1]) + (p[fc][2] + p[fc][3]);
    }
    lrun += (rsv[0] + rsv[1]) + (rsv[2] + rsv[3]);   // partial: no shuffles

    // P -> bf16 -> per-wave LDS (k-contiguous b64 stores, swizzled)
    #pragma unroll
    for (int fc = 0; fc < 4; ++fc) {
      u16x4 q4;
      #pragma unroll
      for (int j = 0; j < 4; ++j) q4[j] = f2bf(p[fc][j]);
      *reinterpret_cast<u16x4*>(
          Pw + lr*128 + (((fc*4 + lg) ^ ((lr & 7) << 1))*8)) = q4;
    }
    // same-wave LDS RAW fence (per-wave Pt; no block barrier needed)
    asm volatile("s_waitcnt lgkmcnt(0)" ::: "memory");
    __builtin_amdgcn_sched_barrier(0);

    // PV: O^T[d][q] += V^T[d][k] * P^T[k][q]; V fragments straight from global
    __builtin_amdgcn_s_setprio(1);
    #pragma unroll
    for (int kk = 0; kk < 2; ++kk) {
      u16x8 pf = *reinterpret_cast<const u16x8*>(
          Pw + lr*128 + (((kk*8 + lg*2) ^ ((lr & 7) << 1))*8));
      #pragma unroll
      for (int fc = 0; fc < 4; ++fc) {
        u16x8 vf = *reinterpret_cast<const u16x8*>(
            vbase + (size_t)(fc*16)*SEQ + kt0 + kk*32);
        acc[fc] = mfma16(vf, pf, acc[fc]);
      }
    }
    __builtin_amdgcn_s_setprio(0);
  }

  // epilogue: combine partial l across the 4 lg-lanes of each q-row, normalize
  float lt = lrun;
  lt += __shfl_xor(lt, 16);
  lt += __shfl_xor(lt, 32);
  const float inv = 1.0f / lt;

  const int b = bh / HEADS, h = bh % HEADS;
  #pragma unroll
  for (int fc = 0; fc < 4; ++fc) {
    u16x4 o4;
    #pragma unroll
    for (int j = 0; j < 4; ++j) o4[j] = f2bf(acc[fc][j] * inv);
    *reinterpret_cast<u16x4*>(
        av + ((size_t)(b*SEQ + qrow))*EMB + h*64 + fc*16 + lg*4) = o4;
  }
}

// ---------------- launcher: 4 kernels ----------------
extern "C" void kernel_launch(void* const* d_in, const int* in_sizes, int n_in,
                              void* d_out, int out_size, void* d_ws, size_t ws_size,
                              hipStream_t stream) {
  const float* xq_f = (const float*)d_in[0];
  const float* xk_f = (const float*)d_in[1];
  const float* xv_f = (const float*)d_in[2];
  const float* Wq = (const float*)d_in[3];
  const float* bq = (const float*)d_in[4];
  const float* Wk = (const float*)d_in[5];
  const float* bk = (const float*)d_in[6];
  const float* Wv = (const float*)d_in[7];
  const float* bv = (const float*)d_in[8];
  const float* Wo = (const float*)d_in[9];
  const float* bo = (const float*)d_in[10];

  const size_t NX = (size_t)NTOK*EMB;
  const size_t NW = (size_t)EMB*EMB;
  u16* Xc0 = (u16*)d_ws;
  u16* Xc1 = Xc0 + NX;
  u16* Xc2 = Xc1 + NX;
  u16* Wc0 = Xc2 + NX;
  u16* Wc1 = Wc0 + NW;
  u16* Wc2 = Wc1 + NW;
  u16* Wc3 = Wc2 + NW;
  u16* Qh  = Wc3 + NW;
  u16* Kh  = Qh + NX;
  u16* Vh  = Kh + NX;        // [B][H][DKV][SEQ] (V^T)
  u16* Xb  = Xc0;            // attn out aliases Xc (dead after qkv)

  const float csc = 0.125f * 1.4426950408889634f;

  cast_all_k<<<dim3(2048), dim3(256), 0, stream>>>(
      xq_f, xk_f, xv_f, Wq, Wk, Wv, Wo,
      Xc0, Xc1, Xc2, Wc0, Wc1, Wc2, Wc3, csc);

  qkv_k<<<dim3(NTOK/128, EMB/128, 3), dim3(256), 0, stream>>>(
      Xc0, Xc1, Xc2, Wc0, Wc1, Wc2, bq, bk, bv, Qh, Kh, Vh, csc);

  flash_attn_k<<<dim3(SEQ/64 * BATCH*HEADS), dim3(256), 0, stream>>>(Qh, Kh, Vh, Xb);

  gemm_out_k<<<dim3(NTOK/128, EMB/128), dim3(256), 0, stream>>>(Xb, Wc3, bo, (float*)d_out);
}

// Round 12
// 118.252 us; speedup vs baseline: 1.9504x; 1.9504x over previous
//
#include <hip/hip_runtime.h>
#include <hip/hip_bf16.h>

#define EMB 768
#define HEADS 12
#define DKV 64
#define BATCH 2
#define SEQ 2048
#define NTOK (BATCH*SEQ)   // 4096

typedef float f32x4 __attribute__((ext_vector_type(4)));
typedef float f32x16 __attribute__((ext_vector_type(16)));
typedef unsigned short u16;
typedef unsigned int u32;
typedef u16 u16x8 __attribute__((ext_vector_type(8)));
typedef u16 u16x4 __attribute__((ext_vector_type(4)));
typedef u32 u32x4 __attribute__((ext_vector_type(4)));
typedef __bf16 bf16x8 __attribute__((ext_vector_type(8)));

__device__ __forceinline__ u16 f2bf(float f) {
  return __builtin_bit_cast(u16, (__bf16)f);
}
__device__ __forceinline__ float fexp2(float x) {
#if __has_builtin(__builtin_amdgcn_exp2f)
  return __builtin_amdgcn_exp2f(x);
#else
  return exp2f(x);
#endif
}
__device__ __forceinline__ f32x4 mfma16(u16x8 a, u16x8 b, f32x4 c) {
  return __builtin_amdgcn_mfma_f32_16x16x32_bf16(
      __builtin_bit_cast(bf16x8, a), __builtin_bit_cast(bf16x8, b), c, 0, 0, 0);
}
__device__ __forceinline__ f32x16 mfma32(u16x8 a, u16x8 b, f32x16 c) {
  return __builtin_amdgcn_mfma_f32_32x32x16_bf16(
      __builtin_bit_cast(bf16x8, a), __builtin_bit_cast(bf16x8, b), c, 0, 0, 0);
}
// async global->LDS, 16B/lane; LDS dest must be wave-uniform base + lane*16
__device__ __forceinline__ void gload16(const void* g, void* l) {
  __builtin_amdgcn_global_load_lds(
      (const __attribute__((address_space(1))) void*)g,
      (__attribute__((address_space(3))) void*)l, 16, 0, 0);
}

// ---------------- fused cast pass: 3 x's + 4 W's fp32 -> bf16 ----------------
__global__ void cast_all_k(
    const float* __restrict__ x0, const float* __restrict__ x1, const float* __restrict__ x2,
    const float* __restrict__ w0, const float* __restrict__ w1,
    const float* __restrict__ w2, const float* __restrict__ w3,
    u16* __restrict__ X0, u16* __restrict__ X1, u16* __restrict__ X2,
    u16* __restrict__ W0, u16* __restrict__ W1, u16* __restrict__ W2, u16* __restrict__ W3,
    float wscale0)
{
  const int NX = NTOK*EMB/8;   // 393216
  const int NW = EMB*EMB/8;    // 73728
  const int total = 3*NX + 4*NW;
  int i = blockIdx.x*256 + threadIdx.x;
  for (; i < total; i += gridDim.x*256) {
    const float* s; u16* d; int off; float sc = 1.f;
    if (i < 3*NX) {
      int which = i / NX; off = i - which*NX;
      s = which==0 ? x0 : which==1 ? x1 : x2;
      d = which==0 ? X0 : which==1 ? X1 : X2;
    } else {
      int j = i - 3*NX; int which = j / NW; off = j - which*NW;
      s = which==0 ? w0 : which==1 ? w1 : which==2 ? w2 : w3;
      d = which==0 ? W0 : which==1 ? W1 : which==2 ? W2 : W3;
      if (which == 0) sc = wscale0;
    }
    float4 a = reinterpret_cast<const float4*>(s)[off*2];
    float4 b = reinterpret_cast<const float4*>(s)[off*2+1];
    u16x8 o;
    o[0]=f2bf(a.x*sc); o[1]=f2bf(a.y*sc); o[2]=f2bf(a.z*sc); o[3]=f2bf(a.w*sc);
    o[4]=f2bf(b.x*sc); o[5]=f2bf(b.y*sc); o[6]=f2bf(b.z*sc); o[7]=f2bf(b.w*sc);
    reinterpret_cast<u16x8*>(d)[off] = o;
  }
}

// ---------------- GEMM core, m97 structure (unchanged from round 9) ----------------
template<int MODE>
__device__ __forceinline__ void gemm_core(
    const u16* __restrict__ A, const u16* __restrict__ Bm,
    const float* __restrict__ bias, float bscale, void* __restrict__ outp,
    u16* __restrict__ At, u16* __restrict__ Bt, int m0, int n0)
{
  const int t = threadIdx.x;
  const int w = t >> 6, lane = t & 63, lg = lane >> 4, lr = lane & 15;
  const int wr = w >> 1, wc = w & 1;

  f32x4 acc[4][4] = {};

  const int crow = (w*4)*8 + (lane >> 3);
  const int csl  = lane & 7;

  auto STAGE = [&](int kb) {
    #pragma unroll
    for (int i = 0; i < 4; ++i) {
      int row = crow + i*8;
      int sg = csl ^ (row & 7);
      gload16(A  + (size_t)(m0+row)*EMB + kb + sg*8, &At[(w*4+i)*512]);
      gload16(Bm + (size_t)(n0+row)*EMB + kb + sg*8, &Bt[(w*4+i)*512]);
    }
  };

  auto COMPUTE = [&]() {
    u16x8 af[4][2], bf[4][2];
    #pragma unroll
    for (int fm = 0; fm < 4; ++fm)
      #pragma unroll
      for (int kk = 0; kk < 2; ++kk) {
        int r = wr*64 + fm*16 + lr;
        int p = (lg + 4*kk) ^ (r & 7);
        af[fm][kk] = *reinterpret_cast<const u16x8*>(&At[r*64 + p*8]);
      }
    #pragma unroll
    for (int fn = 0; fn < 4; ++fn)
      #pragma unroll
      for (int kk = 0; kk < 2; ++kk) {
        int r = wc*64 + fn*16 + lr;
        int p = (lg + 4*kk) ^ (r & 7);
        bf[fn][kk] = *reinterpret_cast<const u16x8*>(&Bt[r*64 + p*8]);
      }
    __builtin_amdgcn_s_setprio(1);
    #pragma unroll
    for (int fm = 0; fm < 4; ++fm)
      #pragma unroll
      for (int fn = 0; fn < 4; ++fn)
        #pragma unroll
        for (int kk = 0; kk < 2; ++kk)
          acc[fm][fn] = mfma16(af[fm][kk], bf[fn][kk], acc[fm][fn]);
    __builtin_amdgcn_s_setprio(0);
  };

  const int NSTEP = EMB/64;   // 12
  #pragma unroll
  for (int ts = 0; ts < NSTEP; ++ts) {
    STAGE(ts*64);
    __syncthreads();
    COMPUTE();
    if (ts+1 < NSTEP) __syncthreads();
  }

  #pragma unroll
  for (int fm = 0; fm < 4; ++fm)
    #pragma unroll
    for (int fn = 0; fn < 4; ++fn) {
      const int mb = m0 + wr*64 + fm*16 + lg*4;
      const int e  = n0 + wc*64 + fn*16 + lr;
      if constexpr (MODE == 2) {
        int bb = mb >> 11, sb = mb & 2047, h = e >> 6, d = e & 63;
        u16x4 o4;
        #pragma unroll
        for (int j = 0; j < 4; ++j) o4[j] = f2bf(acc[fm][fn][j] + bias[e]*bscale);
        *reinterpret_cast<u16x4*>(
            reinterpret_cast<u16*>(outp) + (((size_t)(bb*HEADS+h))*DKV + d)*SEQ + sb) = o4;
      } else {
        #pragma unroll
        for (int j = 0; j < 4; ++j) {
          int m = mb + j;
          float val = acc[fm][fn][j] + bias[e]*bscale;
          if constexpr (MODE == 0) {
            int bb = m >> 11, s = m & 2047, h = e >> 6, d = e & 63;
            reinterpret_cast<u16*>(outp)[(((size_t)(bb*HEADS+h))*SEQ + s)*DKV + d] = f2bf(val);
          } else {
            reinterpret_cast<float*>(outp)[(size_t)m*EMB + e] = val;
          }
        }
      }
    }
}

__global__ __launch_bounds__(256) void qkv_k(
    const u16* __restrict__ Xq, const u16* __restrict__ Xk, const u16* __restrict__ Xv,
    const u16* __restrict__ Wq, const u16* __restrict__ Wk, const u16* __restrict__ Wv,
    const float* __restrict__ bq, const float* __restrict__ bk, const float* __restrict__ bv,
    u16* __restrict__ Qh, u16* __restrict__ Kh, u16* __restrict__ Vh, float csc)
{
  __shared__ __align__(16) u16 At[128*64];
  __shared__ __align__(16) u16 Bt[128*64];
  const int m0 = blockIdx.x*128, n0 = blockIdx.y*128;
  const int z = blockIdx.z;
  if (z == 0)
    gemm_core<0>(Xq, Wq, bq, csc, Qh, At, Bt, m0, n0);
  else if (z == 1)
    gemm_core<0>(Xk, Wk, bk, 1.f, Kh, At, Bt, m0, n0);
  else
    gemm_core<2>(Xv, Wv, bv, 1.f, Vh, At, Bt, m0, n0);
}

__global__ __launch_bounds__(256) void gemm_out_k(
    const u16* __restrict__ A, const u16* __restrict__ Bm,
    const float* __restrict__ bias, float* __restrict__ outp)
{
  __shared__ __align__(16) u16 At[128*64];
  __shared__ __align__(16) u16 Bt[128*64];
  gemm_core<1>(A, Bm, bias, 1.f, outp, At, Bt, blockIdx.x*128, blockIdx.y*128);
}

// ---------------- flash attention: mfma32, register-resident P ----------------
// 2 waves/block; wave owns 32 q-rows x ALL 64 keys of each tile (no key-split,
// no merge). S^T = mfma32(K,Q) per 32-key subtile kb: lane holds col q=lane&31,
// rows key=(reg&3)+8*(reg>>2)+4*hi+32*kb [m74/m101; r10-verified]. Per-lane
// softmax over 32 local scores (partner lane^32 holds the other 32).
// PV: O^T = mfma32(V^T, P): B-frag for k-slice ks needs keys 16ks+8hi+j; lane
// owns {0-3,8-11}+4hi -> exchange 2 packed words with lane^32 via __shfl_xor
// (T12 mechanism) -> P never touches LDS. K/V^T staged via global_load_lds
// (pre-swizzled source, rule #21), double-buffered, ONE barrier/tile.
__global__ __launch_bounds__(128) void flash_attn_k(
    const u16* __restrict__ Q, const u16* __restrict__ K, const u16* __restrict__ VT,
    u16* __restrict__ av)
{
  __shared__ __align__(16) u16 Kt[2][64*64];   // [key][d], phys8 = (d/8)^(key&7)
  __shared__ __align__(16) u16 Vt[2][64*64];   // [d][key], phys8 = (key/8)^(d&7)

  const int t = threadIdx.x;                   // 0..127
  const int w = t >> 6, lane = t & 63;
  const int hi = lane >> 5, q32 = lane & 31;
  const int qb = blockIdx.x, bh = blockIdx.y;
  const u16* Qb = Q  + (size_t)bh*SEQ*DKV;
  const u16* Kb = K  + (size_t)bh*SEQ*DKV;
  const u16* Vb = VT + (size_t)bh*DKV*SEQ;

  const int qrow = qb*64 + w*32 + q32;
  u16x8 qf[4];                                 // B-frag: col=q, k=ks*16+hi*8+j
  #pragma unroll
  for (int ks = 0; ks < 4; ++ks)
    qf[ks] = *reinterpret_cast<const u16x8*>(Qb + (size_t)qrow*DKV + ks*16 + hi*8);

  f32x16 acc0 = {}, acc1 = {};   // O^T: col=q, row d=(r&3)+8*(r>>2)+4hi (+32*db)
  float mrun = -1e30f, lrun = 0.f;   // lrun: partial over this lane's 32 keys

  auto STAGE = [&](int kt0, int bi) {
    #pragma unroll
    for (int i = 0; i < 4; ++i) {
      int c = i*128 + t;                   // 16B chunk 0..511
      int row = c >> 3, sl = c & 7;
      int sg = sl ^ (row & 7);             // pre-swizzled source slot
      gload16(Kb + (size_t)(kt0+row)*DKV + sg*8, &Kt[bi][c*8]);
    }
    #pragma unroll
    for (int i = 0; i < 4; ++i) {
      int c = i*128 + t;
      int row = c >> 3, sl = c & 7;        // row = d
      int sg = sl ^ (row & 7);
      gload16(Vb + (size_t)row*SEQ + kt0 + sg*8, &Vt[bi][c*8]);
    }
  };

  const int NT = SEQ/64;   // 32

#define TILE(bi, kt)                                                          \
  do {                                                                        \
    if ((kt)+1 < NT) STAGE(((kt)+1)*64, (bi)^1);                              \
    f32x16 s0 = {}, s1 = {};                                                  \
    __builtin_amdgcn_s_setprio(1);                                            \
    _Pragma("unroll")                                                         \
    for (int ks = 0; ks < 4; ++ks) {                                          \
      int key0 = q32, key1 = 32 + q32;                                        \
      int ph = (2*ks + hi) ^ (q32 & 7);                                       \
      u16x8 kf0 = *reinterpret_cast<const u16x8*>(&Kt[bi][key0*64 + ph*8]);   \
      u16x8 kf1 = *reinterpret_cast<const u16x8*>(&Kt[bi][key1*64 + ph*8]);   \
      s0 = mfma32(kf0, qf[ks], s0);                                           \
      s1 = mfma32(kf1, qf[ks], s1);                                           \
    }                                                                         \
    __builtin_amdgcn_s_setprio(0);                                            \
    float x0 = fmaxf(fmaxf(s0[0], s0[1]), fmaxf(s0[2], s0[3]));               \
    float x1 = fmaxf(fmaxf(s0[4], s0[5]), fmaxf(s0[6], s0[7]));               \
    float x2 = fmaxf(fmaxf(s0[8], s0[9]), fmaxf(s0[10], s0[11]));             \
    float x3 = fmaxf(fmaxf(s0[12], s0[13]), fmaxf(s0[14], s0[15]));           \
    float x4 = fmaxf(fmaxf(s1[0], s1[1]), fmaxf(s1[2], s1[3]));               \
    float x5 = fmaxf(fmaxf(s1[4], s1[5]), fmaxf(s1[6], s1[7]));               \
    float x6 = fmaxf(fmaxf(s1[8], s1[9]), fmaxf(s1[10], s1[11]));             \
    float x7 = fmaxf(fmaxf(s1[12], s1[13]), fmaxf(s1[14], s1[15]));           \
    float pmax = fmaxf(fmaxf(fmaxf(x0, x1), fmaxf(x2, x3)),                   \
                       fmaxf(fmaxf(x4, x5), fmaxf(x6, x7)));                  \
    if (__any(pmax > mrun + 8.f)) {                                           \
      float pm = fmaxf(pmax, __shfl_xor(pmax, 32));                           \
      float mnew = fmaxf(mrun, pm);                                           \
      float corr = fexp2(mrun - mnew);                                        \
      mrun = mnew; lrun *= corr;                                              \
      acc0 = acc0 * corr;                                                     \
      acc1 = acc1 * corr;                                                     \
    }                                                                         \
    u32 pw0[8], pw1[8];                                                       \
    float psum = 0.f;                                                         \
    _Pragma("unroll")                                                         \
    for (int wi = 0; wi < 8; ++wi) {                                          \
      float e0 = fexp2(s0[2*wi]   - mrun);                                    \
      float e1 = fexp2(s0[2*wi+1] - mrun);                                    \
      psum += e0 + e1;                                                        \
      pw0[wi] = (u32)f2bf(e0) | ((u32)f2bf(e1) << 16);                        \
      float f0 = fexp2(s1[2*wi]   - mrun);                                    \
      float f1 = fexp2(s1[2*wi+1] - mrun);                                    \
      psum += f0 + f1;                                                        \
      pw1[wi] = (u32)f2bf(f0) | ((u32)f2bf(f1) << 16);                        \
    }                                                                         \
    lrun += psum;                                                             \
    _Pragma("unroll")                                                         \
    for (int ks = 0; ks < 4; ++ks) {                                          \
      const int sh = ks & 1;                                                  \
      u32 A0 = (ks < 2) ? pw0[4*sh]   : pw1[4*sh];                            \
      u32 A1 = (ks < 2) ? pw0[4*sh+1] : pw1[4*sh+1];                          \
      u32 B0 = (ks < 2) ? pw0[4*sh+2] : pw1[4*sh+2];                          \
      u32 B1 = (ks < 2) ? pw0[4*sh+3] : pw1[4*sh+3];                          \
      u32 r0 = __shfl_xor(hi ? A0 : B0, 32);                                  \
      u32 r1 = __shfl_xor(hi ? A1 : B1, 32);                                  \
      u32x4 pfw;                                                              \
      pfw[0] = hi ? r0 : A0;  pfw[1] = hi ? r1 : A1;                          \
      pfw[2] = hi ? B0 : r0;  pfw[3] = hi ? B1 : r1;                          \
      u16x8 pf = __builtin_bit_cast(u16x8, pfw);                              \
      int ph = (2*ks + hi) ^ (q32 & 7);                                       \
      u16x8 v0 = *reinterpret_cast<const u16x8*>(&Vt[bi][q32*64 + ph*8]);     \
      u16x8 v1 = *reinterpret_cast<const u16x8*>(&Vt[bi][(32+q32)*64 + ph*8]);\
      __builtin_amdgcn_s_setprio(1);                                          \
      acc0 = mfma32(v0, pf, acc0);                                            \
      acc1 = mfma32(v1, pf, acc1);                                            \
      __builtin_amdgcn_s_setprio(0);                                          \
    }                                                                         \
    __syncthreads();                                                          \
  } while (0)

  STAGE(0, 0);
  __syncthreads();
  for (int kt = 0; kt < NT; kt += 2) {
    TILE(0, kt);
    TILE(1, kt+1);
  }
#undef TILE

  // epilogue: combine partner partial l, normalize, store O[q][d]
  float lt = lrun + __shfl_xor(lrun, 32);
  const float inv = 1.0f / lt;
  const int b = bh / HEADS, h = bh % HEADS;
  u16* op = av + ((size_t)(b*SEQ + qrow))*EMB + h*64;
  #pragma unroll
  for (int g = 0; g < 4; ++g) {
    u16x4 o4a, o4b;
    #pragma unroll
    for (int j = 0; j < 4; ++j) {
      o4a[j] = f2bf(acc0[g*4+j] * inv);
      o4b[j] = f2bf(acc1[g*4+j] * inv);
    }
    *reinterpret_cast<u16x4*>(op + g*8 + hi*4) = o4a;          // d = 8g+4hi+j
    *reinterpret_cast<u16x4*>(op + 32 + g*8 + hi*4) = o4b;     // d = 32+8g+4hi+j
  }
}

// ---------------- launcher: 4 kernels ----------------
extern "C" void kernel_launch(void* const* d_in, const int* in_sizes, int n_in,
                              void* d_out, int out_size, void* d_ws, size_t ws_size,
                              hipStream_t stream) {
  const float* xq_f = (const float*)d_in[0];
  const float* xk_f = (const float*)d_in[1];
  const float* xv_f = (const float*)d_in[2];
  const float* Wq = (const float*)d_in[3];
  const float* bq = (const float*)d_in[4];
  const float* Wk = (const float*)d_in[5];
  const float* bk = (const float*)d_in[6];
  const float* Wv = (const float*)d_in[7];
  const float* bv = (const float*)d_in[8];
  const float* Wo = (const float*)d_in[9];
  const float* bo = (const float*)d_in[10];

  const size_t NX = (size_t)NTOK*EMB;
  const size_t NW = (size_t)EMB*EMB;
  u16* Xc0 = (u16*)d_ws;
  u16* Xc1 = Xc0 + NX;
  u16* Xc2 = Xc1 + NX;
  u16* Wc0 = Xc2 + NX;
  u16* Wc1 = Wc0 + NW;
  u16* Wc2 = Wc1 + NW;
  u16* Wc3 = Wc2 + NW;
  u16* Qh  = Wc3 + NW;
  u16* Kh  = Qh + NX;
  u16* Vh  = Kh + NX;        // [B][H][DKV][SEQ] (V^T)
  u16* Xb  = Xc0;            // attn out aliases Xc (dead after qkv)

  const float csc = 0.125f * 1.4426950408889634f;

  cast_all_k<<<dim3(2048), dim3(256), 0, stream>>>(
      xq_f, xk_f, xv_f, Wq, Wk, Wv, Wo,
      Xc0, Xc1, Xc2, Wc0, Wc1, Wc2, Wc3, csc);

  qkv_k<<<dim3(NTOK/128, EMB/128, 3), dim3(256), 0, stream>>>(
      Xc0, Xc1, Xc2, Wc0, Wc1, Wc2, bq, bk, bv, Qh, Kh, Vh, csc);

  flash_attn_k<<<dim3(SEQ/64, BATCH*HEADS), dim3(128), 0, stream>>>(Qh, Kh, Vh, Xb);

  gemm_out_k<<<dim3(NTOK/128, EMB/128), dim3(256), 0, stream>>>(Xb, Wc3, bo, (float*)d_out);
}

// Round 13
// 96.394 us; speedup vs baseline: 2.3926x; 1.2268x over previous
//
#include <hip/hip_runtime.h>
#include <hip/hip_bf16.h>

#define EMB 768
#define HEADS 12
#define DKV 64
#define BATCH 2
#define SEQ 2048
#define NTOK (BATCH*SEQ)   // 4096

typedef float f32x4 __attribute__((ext_vector_type(4)));
typedef unsigned short u16;
typedef u16 u16x8 __attribute__((ext_vector_type(8)));
typedef u16 u16x4 __attribute__((ext_vector_type(4)));
typedef __bf16 bf16x8 __attribute__((ext_vector_type(8)));

__device__ __forceinline__ u16 f2bf(float f) {
  return __builtin_bit_cast(u16, (__bf16)f);
}
__device__ __forceinline__ float fexp2(float x) {
#if __has_builtin(__builtin_amdgcn_exp2f)
  return __builtin_amdgcn_exp2f(x);
#else
  return exp2f(x);
#endif
}
__device__ __forceinline__ f32x4 mfma16(u16x8 a, u16x8 b, f32x4 c) {
  return __builtin_amdgcn_mfma_f32_16x16x32_bf16(
      __builtin_bit_cast(bf16x8, a), __builtin_bit_cast(bf16x8, b), c, 0, 0, 0);
}
// async global->LDS, 16B/lane; LDS dest must be wave-uniform base (+ lane*16 impl.)
__device__ __forceinline__ void gload16(const void* g, void* l) {
  __builtin_amdgcn_global_load_lds(
      (const __attribute__((address_space(1))) void*)g,
      (__attribute__((address_space(3))) void*)l, 16, 0, 0);
}

// ---------------- fused cast pass: 3 x's + 4 W's fp32 -> bf16 ----------------
__global__ void cast_all_k(
    const float* __restrict__ x0, const float* __restrict__ x1, const float* __restrict__ x2,
    const float* __restrict__ w0, const float* __restrict__ w1,
    const float* __restrict__ w2, const float* __restrict__ w3,
    u16* __restrict__ X0, u16* __restrict__ X1, u16* __restrict__ X2,
    u16* __restrict__ W0, u16* __restrict__ W1, u16* __restrict__ W2, u16* __restrict__ W3,
    float wscale0)
{
  const int NX = NTOK*EMB/8;   // 393216
  const int NW = EMB*EMB/8;    // 73728
  const int total = 3*NX + 4*NW;
  int i = blockIdx.x*256 + threadIdx.x;
  for (; i < total; i += gridDim.x*256) {
    const float* s; u16* d; int off; float sc = 1.f;
    if (i < 3*NX) {
      int which = i / NX; off = i - which*NX;
      s = which==0 ? x0 : which==1 ? x1 : x2;
      d = which==0 ? X0 : which==1 ? X1 : X2;
    } else {
      int j = i - 3*NX; int which = j / NW; off = j - which*NW;
      s = which==0 ? w0 : which==1 ? w1 : which==2 ? w2 : w3;
      d = which==0 ? W0 : which==1 ? W1 : which==2 ? W2 : W3;
      if (which == 0) sc = wscale0;
    }
    float4 a = reinterpret_cast<const float4*>(s)[off*2];
    float4 b = reinterpret_cast<const float4*>(s)[off*2+1];
    u16x8 o;
    o[0]=f2bf(a.x*sc); o[1]=f2bf(a.y*sc); o[2]=f2bf(a.z*sc); o[3]=f2bf(a.w*sc);
    o[4]=f2bf(b.x*sc); o[5]=f2bf(b.y*sc); o[6]=f2bf(b.z*sc); o[7]=f2bf(b.w*sc);
    reinterpret_cast<u16x8*>(d)[off] = o;
  }
}

// ---------------- GEMM core, m97 schedule retiled 64x128 ----------------
// BM=64, BN=128, BK=64; 4 waves (2x2), each wave 32x64 out (2x4 16^2 frags,
// 16 MFMA/step, 12 ds_read_b128). Grid-limited regime fix: 64-row tiles double
// the grid (1152 blocks = 4.5/CU) vs 128^2 (576 = 2.25/CU). Staging via
// global_load_lds w=16: LDS LINEAR dest (1KB chunk per wave-load), global
// source pre-swizzled sg = sl ^ (row&7) (rule #21). Single-buffer 24 KB LDS,
// 2 barriers/step. All inputs bf16.
// MODE 0: bf16 head-split [B][H][S][DKV] (+bias*bscale).
// MODE 1: fp32 [M][EMB] (+bias). MODE 2: bf16 head-split transposed [B][H][DKV][SEQ].
template<int MODE>
__device__ __forceinline__ void gemm_core(
    const u16* __restrict__ A, const u16* __restrict__ Bm,
    const float* __restrict__ bias, float bscale, void* __restrict__ outp,
    u16* __restrict__ At, u16* __restrict__ Bt, int m0, int n0)
{
  const int t = threadIdx.x;
  const int w = t >> 6, lane = t & 63, lg = lane >> 4, lr = lane & 15;
  const int wr = w >> 1, wc = w & 1;

  f32x4 acc[2][4] = {};

  const int lrow = lane >> 3;          // lane's row within an 8-row chunk
  const int csl  = lane & 7;           // lane's 16B slot within the row

  auto STAGE = [&](int kb) {
    // A tile: 8 chunks of 1KB (8 rows x 8 slots); wave w -> chunks w*2+i
    #pragma unroll
    for (int i = 0; i < 2; ++i) {
      int ci = w*2 + i;
      int row = ci*8 + lrow;
      int sg = csl ^ (row & 7);
      gload16(A + (size_t)(m0+row)*EMB + kb + sg*8, &At[ci*512]);
    }
    // B tile: 16 chunks; wave w -> chunks w*4+i
    #pragma unroll
    for (int i = 0; i < 4; ++i) {
      int ci = w*4 + i;
      int row = ci*8 + lrow;
      int sg = csl ^ (row & 7);
      gload16(Bm + (size_t)(n0+row)*EMB + kb + sg*8, &Bt[ci*512]);
    }
  };

  auto COMPUTE = [&]() {
    u16x8 af[2][2], bf[4][2];
    #pragma unroll
    for (int fm = 0; fm < 2; ++fm)
      #pragma unroll
      for (int kk = 0; kk < 2; ++kk) {
        int r = wr*32 + fm*16 + lr;
        int p = (lg + 4*kk) ^ (r & 7);
        af[fm][kk] = *reinterpret_cast<const u16x8*>(&At[r*64 + p*8]);
      }
    #pragma unroll
    for (int fn = 0; fn < 4; ++fn)
      #pragma unroll
      for (int kk = 0; kk < 2; ++kk) {
        int r = wc*64 + fn*16 + lr;
        int p = (lg + 4*kk) ^ (r & 7);
        bf[fn][kk] = *reinterpret_cast<const u16x8*>(&Bt[r*64 + p*8]);
      }
    __builtin_amdgcn_s_setprio(1);
    #pragma unroll
    for (int fm = 0; fm < 2; ++fm)
      #pragma unroll
      for (int fn = 0; fn < 4; ++fn)
        #pragma unroll
        for (int kk = 0; kk < 2; ++kk)
          acc[fm][fn] = mfma16(af[fm][kk], bf[fn][kk], acc[fm][fn]);
    __builtin_amdgcn_s_setprio(0);
  };

  const int NSTEP = EMB/64;   // 12
  #pragma unroll
  for (int ts = 0; ts < NSTEP; ++ts) {
    STAGE(ts*64);
    __syncthreads();            // vmcnt(0) drained -> tile visible
    COMPUTE();
    if (ts+1 < NSTEP) __syncthreads();   // readers done before overwrite
  }

  // epilogue: C layout col = lane&15, row = (lane>>4)*4 + j  [measured m89]
  #pragma unroll
  for (int fm = 0; fm < 2; ++fm)
    #pragma unroll
    for (int fn = 0; fn < 4; ++fn) {
      const int mb = m0 + wr*32 + fm*16 + lg*4;
      const int e  = n0 + wc*64 + fn*16 + lr;
      if constexpr (MODE == 2) {
        int bb = mb >> 11, sb = mb & 2047, h = e >> 6, d = e & 63;
        u16x4 o4;
        #pragma unroll
        for (int j = 0; j < 4; ++j) o4[j] = f2bf(acc[fm][fn][j] + bias[e]*bscale);
        *reinterpret_cast<u16x4*>(
            reinterpret_cast<u16*>(outp) + (((size_t)(bb*HEADS+h))*DKV + d)*SEQ + sb) = o4;
      } else {
        #pragma unroll
        for (int j = 0; j < 4; ++j) {
          int m = mb + j;
          float val = acc[fm][fn][j] + bias[e]*bscale;
          if constexpr (MODE == 0) {
            int bb = m >> 11, s = m & 2047, h = e >> 6, d = e & 63;
            reinterpret_cast<u16*>(outp)[(((size_t)(bb*HEADS+h))*SEQ + s)*DKV + d] = f2bf(val);
          } else {
            reinterpret_cast<float*>(outp)[(size_t)m*EMB + e] = val;
          }
        }
      }
    }
}

__global__ __launch_bounds__(256) void qkv_k(
    const u16* __restrict__ Xq, const u16* __restrict__ Xk, const u16* __restrict__ Xv,
    const u16* __restrict__ Wq, const u16* __restrict__ Wk, const u16* __restrict__ Wv,
    const float* __restrict__ bq, const float* __restrict__ bk, const float* __restrict__ bv,
    u16* __restrict__ Qh, u16* __restrict__ Kh, u16* __restrict__ Vh, float csc)
{
  __shared__ __align__(16) u16 At[64*64];      // 8 KB
  __shared__ __align__(16) u16 Bt[128*64];     // 16 KB
  const int m0 = blockIdx.x*64, n0 = blockIdx.y*128;
  const int z = blockIdx.z;
  if (z == 0)
    gemm_core<0>(Xq, Wq, bq, csc, Qh, At, Bt, m0, n0);
  else if (z == 1)
    gemm_core<0>(Xk, Wk, bk, 1.f, Kh, At, Bt, m0, n0);
  else
    gemm_core<2>(Xv, Wv, bv, 1.f, Vh, At, Bt, m0, n0);
}

__global__ __launch_bounds__(256) void gemm_out_k(
    const u16* __restrict__ A, const u16* __restrict__ Bm,
    const float* __restrict__ bias, float* __restrict__ outp)
{
  __shared__ __align__(16) u16 At[64*64];
  __shared__ __align__(16) u16 Bt[128*64];
  gemm_core<1>(A, Bm, bias, 1.f, outp, At, Bt, blockIdx.x*64, blockIdx.y*128);
}

// ---------------- flash attention (r7 exact: best measured 52.1 us) ----------------
// Swapped QK^T, per-lane base-2 softmax, partial-lrun (epilogue reduce),
// defer-max gate (THR=8), K/V double-buffered, 1 barrier/tile, T14 early loads.
__global__ __launch_bounds__(256) void flash_attn_k(
    const u16* __restrict__ Q, const u16* __restrict__ K, const u16* __restrict__ VT,
    u16* __restrict__ av)
{
  __shared__ __align__(16) u16 Kt[2][64*64];     // [key][d] swizzled
  __shared__ __align__(16) u16 Vt[2][64*64];     // [d][key] swizzled
  __shared__ __align__(16) u16 Pt[4][16*64];     // per-wave [q][k] swizzled

  const int t = threadIdx.x;
  const int w = t >> 6, lane = t & 63, lg = lane >> 4, lr = lane & 15;
  const int tr = t >> 3, tsl = t & 7;
  const int qb = blockIdx.x;       // 0..31
  const int bh = blockIdx.y;       // 0..23
  const u16* Qb = Q  + (size_t)bh*SEQ*DKV;
  const u16* Kb = K  + (size_t)bh*SEQ*DKV;
  const u16* Vb = VT + (size_t)bh*DKV*SEQ;

  const int qrow = qb*64 + w*16 + lr;
  u16x8 qf[2];
  qf[0] = *reinterpret_cast<const u16x8*>(Qb + (size_t)qrow*DKV + lg*8);
  qf[1] = *reinterpret_cast<const u16x8*>(Qb + (size_t)qrow*DKV + 32 + lg*8);

  f32x4 acc[4] = {};   // O^T: acc[fc][j] -> d = fc*16+lg*4+j, q = lr
  float mrun = -1e30f, lrun = 0.f;   // lrun = per-lane PARTIAL (16 keys/tile)

  u16x8 ks[2], vs[2];
  auto LOADKV = [&](int kt0) {
    #pragma unroll
    for (int q = 0; q < 2; ++q) {
      int row = q*32 + tr;
      ks[q] = *reinterpret_cast<const u16x8*>(Kb + (size_t)(kt0+row)*DKV + tsl*8);
    }
    #pragma unroll
    for (int q = 0; q < 2; ++q) {
      int d = q*32 + tr;
      vs[q] = *reinterpret_cast<const u16x8*>(Vb + (size_t)d*SEQ + kt0 + tsl*8);
    }
  };

  const int NT = SEQ/64;   // 32
  LOADKV(0);
  {
    #pragma unroll
    for (int q = 0; q < 2; ++q) {
      int row = q*32 + tr;
      *reinterpret_cast<u16x8*>(&Kt[0][row*64 + ((tsl ^ (row & 7))*8)]) = ks[q];
    }
    #pragma unroll
    for (int q = 0; q < 2; ++q) {
      int d = q*32 + tr;
      *reinterpret_cast<u16x8*>(&Vt[0][d*64 + ((tsl ^ (d & 7))*8)]) = vs[q];
    }
  }
  __syncthreads();

  char* Pw = reinterpret_cast<char*>(&Pt[w][0]);

#define TILE(bi, kt)                                                          \
  do {                                                                        \
    if ((kt)+1 < NT) LOADKV(((kt)+1)*64);                                     \
    f32x4 s[4];                                                               \
    __builtin_amdgcn_s_setprio(1);                                            \
    _Pragma("unroll")                                                         \
    for (int fc = 0; fc < 4; ++fc) {                                          \
      f32x4 z = {};                                                           \
      _Pragma("unroll")                                                       \
      for (int kk = 0; kk < 2; ++kk) {                                        \
        int r = fc*16 + lr;                                                   \
        int slot = (lg + 4*kk) ^ (r & 7);                                     \
        u16x8 kf = *reinterpret_cast<const u16x8*>(&Kt[bi][r*64 + slot*8]);   \
        z = mfma16(kf, qf[kk], z);                                            \
      }                                                                       \
      s[fc] = z;                                                              \
    }                                                                         \
    __builtin_amdgcn_s_setprio(0);                                            \
    float a0 = fmaxf(fmaxf(s[0][0], s[0][1]), s[0][2]);                       \
    float a1 = fmaxf(fmaxf(s[0][3], s[1][0]), s[1][1]);                       \
    float a2 = fmaxf(fmaxf(s[1][2], s[1][3]), s[2][0]);                       \
    float a3 = fmaxf(fmaxf(s[2][1], s[2][2]), s[2][3]);                       \
    float a4 = fmaxf(fmaxf(s[3][0], s[3][1]), s[3][2]);                       \
    float pmax = fmaxf(fmaxf(fmaxf(a0, a1), a2),                              \
                       fmaxf(fmaxf(a3, a4), s[3][3]));                        \
    if (__any(pmax > mrun + 8.f)) {   /* rare: full reduce + rescale */       \
      float pm = fmaxf(pmax, __shfl_xor(pmax, 16));                           \
      pm = fmaxf(pm, __shfl_xor(pm, 32));                                     \
      float mnew = fmaxf(mrun, pm);                                           \
      float corr = fexp2(mrun - mnew);                                        \
      mrun = mnew; lrun *= corr;                                              \
      _Pragma("unroll")                                                       \
      for (int fc = 0; fc < 4; ++fc)                                          \
        _Pragma("unroll")                                                     \
        for (int j = 0; j < 4; ++j)                                           \
          acc[fc][j] *= corr;                                                 \
    }                                                                         \
    float p[4][4], rs[4];                                                     \
    _Pragma("unroll")                                                         \
    for (int fc = 0; fc < 4; ++fc) {                                          \
      _Pragma("unroll")                                                       \
      for (int j = 0; j < 4; ++j) p[fc][j] = fexp2(s[fc][j] - mrun);          \
      rs[fc] = (p[fc][0] + p[fc][1]) + (p[fc][2] + p[fc][3]);                 \
    }                                                                         \
    lrun += (rs[0] + rs[1]) + (rs[2] + rs[3]);   /* partial: no shuffles */   \
    _Pragma("unroll")                                                         \
    for (int fc = 0; fc < 4; ++fc) {                                          \
      u16x4 q4;                                                               \
      _Pragma("unroll")                                                       \
      for (int j = 0; j < 4; ++j) q4[j] = f2bf(p[fc][j]);                     \
      *reinterpret_cast<u16x4*>(                                              \
          Pw + lr*128 + (((fc*4 + lg) ^ ((lr & 7) << 1))*8)) = q4;            \
    }                                                                         \
    asm volatile("s_waitcnt lgkmcnt(0)" ::: "memory");                        \
    __builtin_amdgcn_sched_barrier(0);                                        \
    __builtin_amdgcn_s_setprio(1);                                            \
    _Pragma("unroll")                                                         \
    for (int kk = 0; kk < 2; ++kk) {                                          \
      u16x8 pf = *reinterpret_cast<const u16x8*>(                             \
          Pw + lr*128 + (((kk*8 + lg*2) ^ ((lr & 7) << 1))*8));               \
      _Pragma("unroll")                                                       \
      for (int fc = 0; fc < 4; ++fc) {                                        \
        int rv = fc*16 + lr;                                                  \
        int slotv = (lg + 4*kk) ^ (rv & 7);                                   \
        u16x8 vf = *reinterpret_cast<const u16x8*>(&Vt[bi][rv*64 + slotv*8]); \
        acc[fc] = mfma16(vf, pf, acc[fc]);                                    \
      }                                                                       \
    }                                                                         \
    __builtin_amdgcn_s_setprio(0);                                            \
    if ((kt)+1 < NT) {                                                        \
      _Pragma("unroll")                                                       \
      for (int q = 0; q < 2; ++q) {                                           \
        int row = q*32 + tr;                                                  \
        *reinterpret_cast<u16x8*>(                                            \
            &Kt[(bi)^1][row*64 + ((tsl ^ (row & 7))*8)]) = ks[q];             \
      }                                                                       \
      _Pragma("unroll")                                                       \
      for (int q = 0; q < 2; ++q) {                                           \
        int d = q*32 + tr;                                                    \
        *reinterpret_cast<u16x8*>(                                            \
            &Vt[(bi)^1][d*64 + ((tsl ^ (d & 7))*8)]) = vs[q];                 \
      }                                                                       \
    }                                                                         \
    __syncthreads();                                                          \
  } while (0)

  for (int kt = 0; kt < NT; kt += 2) {
    TILE(0, kt);
    TILE(1, kt+1);
  }
#undef TILE

  // epilogue: combine partial l across the 4 lg-lanes of each q-row, normalize
  float lt = lrun;
  lt += __shfl_xor(lt, 16);
  lt += __shfl_xor(lt, 32);
  const float inv = 1.0f / lt;

  const int b = bh / HEADS, h = bh % HEADS;
  #pragma unroll
  for (int fc = 0; fc < 4; ++fc) {
    u16x4 o4;
    #pragma unroll
    for (int j = 0; j < 4; ++j) o4[j] = f2bf(acc[fc][j] * inv);
    *reinterpret_cast<u16x4*>(
        av + ((size_t)(b*SEQ + qrow))*EMB + h*64 + fc*16 + lg*4) = o4;
  }
}

// ---------------- launcher: 4 kernels ----------------
extern "C" void kernel_launch(void* const* d_in, const int* in_sizes, int n_in,
                              void* d_out, int out_size, void* d_ws, size_t ws_size,
                              hipStream_t stream) {
  const float* xq_f = (const float*)d_in[0];
  const float* xk_f = (const float*)d_in[1];
  const float* xv_f = (const float*)d_in[2];
  const float* Wq = (const float*)d_in[3];
  const float* bq = (const float*)d_in[4];
  const float* Wk = (const float*)d_in[5];
  const float* bk = (const float*)d_in[6];
  const float* Wv = (const float*)d_in[7];
  const float* bv = (const float*)d_in[8];
  const float* Wo = (const float*)d_in[9];
  const float* bo = (const float*)d_in[10];

  const size_t NX = (size_t)NTOK*EMB;
  const size_t NW = (size_t)EMB*EMB;
  u16* Xc0 = (u16*)d_ws;
  u16* Xc1 = Xc0 + NX;
  u16* Xc2 = Xc1 + NX;
  u16* Wc0 = Xc2 + NX;
  u16* Wc1 = Wc0 + NW;
  u16* Wc2 = Wc1 + NW;
  u16* Wc3 = Wc2 + NW;
  u16* Qh  = Wc3 + NW;
  u16* Kh  = Qh + NX;
  u16* Vh  = Kh + NX;        // [B][H][DKV][SEQ] (V^T)
  u16* Xb  = Xc0;            // attn out aliases Xc (dead after qkv)

  const float csc = 0.125f * 1.4426950408889634f;

  cast_all_k<<<dim3(2048), dim3(256), 0, stream>>>(
      xq_f, xk_f, xv_f, Wq, Wk, Wv, Wo,
      Xc0, Xc1, Xc2, Wc0, Wc1, Wc2, Wc3, csc);

  qkv_k<<<dim3(NTOK/64, EMB/128, 3), dim3(256), 0, stream>>>(
      Xc0, Xc1, Xc2, Wc0, Wc1, Wc2, bq, bk, bv, Qh, Kh, Vh, csc);

  flash_attn_k<<<dim3(SEQ/64, BATCH*HEADS), dim3(256), 0, stream>>>(Qh, Kh, Vh, Xb);

  gemm_out_k<<<dim3(NTOK/64, EMB/128), dim3(256), 0, stream>>>(Xb, Wc3, bo, (float*)d_out);
}

// Round 14
// 96.006 us; speedup vs baseline: 2.4023x; 1.0040x over previous
//
#include <hip/hip_runtime.h>
#include <hip/hip_bf16.h>

#define EMB 768
#define HEADS 12
#define DKV 64
#define BATCH 2
#define SEQ 2048
#define NTOK (BATCH*SEQ)   // 4096

typedef float f32x4 __attribute__((ext_vector_type(4)));
typedef unsigned short u16;
typedef u16 u16x8 __attribute__((ext_vector_type(8)));
typedef u16 u16x4 __attribute__((ext_vector_type(4)));
typedef __bf16 bf16x8 __attribute__((ext_vector_type(8)));

__device__ __forceinline__ u16 f2bf(float f) {
  return __builtin_bit_cast(u16, (__bf16)f);
}
__device__ __forceinline__ float fexp2(float x) {
#if __has_builtin(__builtin_amdgcn_exp2f)
  return __builtin_amdgcn_exp2f(x);
#else
  return exp2f(x);
#endif
}
__device__ __forceinline__ f32x4 mfma16(u16x8 a, u16x8 b, f32x4 c) {
  return __builtin_amdgcn_mfma_f32_16x16x32_bf16(
      __builtin_bit_cast(bf16x8, a), __builtin_bit_cast(bf16x8, b), c, 0, 0, 0);
}
// async global->LDS, 16B/lane; LDS dest = wave-uniform base + lane*16 (implicit)
__device__ __forceinline__ void gload16(const void* g, void* l) {
  __builtin_amdgcn_global_load_lds(
      (const __attribute__((address_space(1))) void*)g,
      (__attribute__((address_space(3))) void*)l, 16, 0, 0);
}

// ---------------- cast pass: 4 W's fp32 -> bf16 (x casts fused into qkv) ----------------
__global__ void cast_w_k(
    const float* __restrict__ w0, const float* __restrict__ w1,
    const float* __restrict__ w2, const float* __restrict__ w3,
    u16* __restrict__ W0, u16* __restrict__ W1, u16* __restrict__ W2, u16* __restrict__ W3)
{
  const int NW = EMB*EMB/8;    // 73728
  int i = blockIdx.x*256 + threadIdx.x;
  if (i >= 4*NW) return;
  int which = i / NW, off = i - which*NW;
  const float* s = which==0 ? w0 : which==1 ? w1 : which==2 ? w2 : w3;
  u16* d        = which==0 ? W0 : which==1 ? W1 : which==2 ? W2 : W3;
  float4 a = reinterpret_cast<const float4*>(s)[off*2];
  float4 b = reinterpret_cast<const float4*>(s)[off*2+1];
  u16x8 o;
  o[0]=f2bf(a.x); o[1]=f2bf(a.y); o[2]=f2bf(a.z); o[3]=f2bf(a.w);
  o[4]=f2bf(b.x); o[5]=f2bf(b.y); o[6]=f2bf(b.z); o[7]=f2bf(b.w);
  reinterpret_cast<u16x8*>(d)[off] = o;
}

// ---------------- GEMM core, m97 schedule, 64x128 tile ----------------
// BM=64, BN=128, BK=64; 4 waves (2x2), each wave 32x64 out. 1152-block grid.
// W (B-operand) staged via global_load_lds (LDS linear dest, pre-swizzled source,
// rule #21). A-operand: AF32 -> reg-staged from fp32 with in-register cvt
// (x-cast fused; ascale folds the softmax scale for the Q projection);
// else gload like B. Single-buffer LDS 24 KB, 2 barriers/step.
// MODE 0: bf16 head-split [B][H][S][DKV] (+bias*bscale).
// MODE 1: fp32 [M][EMB] (+bias). MODE 2: bf16 head-split transposed [B][H][DKV][SEQ].
template<int MODE, bool AF32>
__device__ __forceinline__ void gemm_core(
    const void* __restrict__ Ap, const u16* __restrict__ Bm,
    const float* __restrict__ bias, float ascale, float bscale,
    void* __restrict__ outp, u16* __restrict__ At, u16* __restrict__ Bt,
    int m0, int n0)
{
  const int t = threadIdx.x;
  const int w = t >> 6, lane = t & 63, lg = lane >> 4, lr = lane & 15;
  const int wr = w >> 1, wc = w & 1;
  const int lrow = lane >> 3, csl = lane & 7;   // gload chunk row/slot

  f32x4 acc[2][4] = {};
  f32x4 raf[2][2];   // AF32 staging regs

  auto A_LOAD = [&](int kb) {   // AF32: issue fp32 A loads early (T14)
    #pragma unroll
    for (int q2 = 0; q2 < 2; ++q2) {
      int c = q2*256 + t, row = c >> 3, sl = c & 7;
      const float* p = (const float*)Ap + (size_t)(m0+row)*EMB + kb + sl*8;
      raf[q2][0] = *reinterpret_cast<const f32x4*>(p);
      raf[q2][1] = *reinterpret_cast<const f32x4*>(p + 4);
    }
  };
  auto A_WRITE = [&]() {        // AF32: cvt + swizzled ds_write
    #pragma unroll
    for (int q2 = 0; q2 < 2; ++q2) {
      int c = q2*256 + t, row = c >> 3, sl = c & 7;
      u16x8 v;
      #pragma unroll
      for (int j = 0; j < 4; ++j) {
        v[j]   = f2bf(raf[q2][0][j] * ascale);
        v[4+j] = f2bf(raf[q2][1][j] * ascale);
      }
      *reinterpret_cast<u16x8*>(&At[row*64 + ((sl ^ (row & 7))*8)]) = v;
    }
  };
  auto A_GLOAD = [&](int kb) {  // !AF32: A via global_load_lds (8 chunks)
    #pragma unroll
    for (int i = 0; i < 2; ++i) {
      int ci = w*2 + i;
      int row = ci*8 + lrow;
      int sg = csl ^ (row & 7);
      gload16((const u16*)Ap + (size_t)(m0+row)*EMB + kb + sg*8, &At[ci*512]);
    }
  };
  auto B_GLOAD = [&](int kb) {  // B via global_load_lds (16 chunks)
    #pragma unroll
    for (int i = 0; i < 4; ++i) {
      int ci = w*4 + i;
      int row = ci*8 + lrow;
      int sg = csl ^ (row & 7);
      gload16(Bm + (size_t)(n0+row)*EMB + kb + sg*8, &Bt[ci*512]);
    }
  };

  auto COMPUTE = [&]() {
    u16x8 af[2][2], bf[4][2];
    #pragma unroll
    for (int fm = 0; fm < 2; ++fm)
      #pragma unroll
      for (int kk = 0; kk < 2; ++kk) {
        int r = wr*32 + fm*16 + lr;
        int p = (lg + 4*kk) ^ (r & 7);
        af[fm][kk] = *reinterpret_cast<const u16x8*>(&At[r*64 + p*8]);
      }
    #pragma unroll
    for (int fn = 0; fn < 4; ++fn)
      #pragma unroll
      for (int kk = 0; kk < 2; ++kk) {
        int r = wc*64 + fn*16 + lr;
        int p = (lg + 4*kk) ^ (r & 7);
        bf[fn][kk] = *reinterpret_cast<const u16x8*>(&Bt[r*64 + p*8]);
      }
    __builtin_amdgcn_s_setprio(1);
    #pragma unroll
    for (int fm = 0; fm < 2; ++fm)
      #pragma unroll
      for (int fn = 0; fn < 4; ++fn)
        #pragma unroll
        for (int kk = 0; kk < 2; ++kk)
          acc[fm][fn] = mfma16(af[fm][kk], bf[fn][kk], acc[fm][fn]);
    __builtin_amdgcn_s_setprio(0);
  };

  const int NSTEP = EMB/64;   // 12
  if constexpr (AF32) {
    A_LOAD(0);
    B_GLOAD(0);
    A_WRITE();
    __syncthreads();
    #pragma unroll
    for (int ts = 0; ts < NSTEP; ++ts) {
      if (ts+1 < NSTEP) A_LOAD((ts+1)*64);   // fp32 loads land under COMPUTE
      COMPUTE();
      if (ts+1 < NSTEP) {
        __syncthreads();                      // readers of step ts done
        B_GLOAD((ts+1)*64);
        A_WRITE();
        __syncthreads();                      // gload vmcnt + ds_writes drained
      }
    }
  } else {
    #pragma unroll
    for (int ts = 0; ts < NSTEP; ++ts) {
      A_GLOAD(ts*64);
      B_GLOAD(ts*64);
      __syncthreads();
      COMPUTE();
      if (ts+1 < NSTEP) __syncthreads();
    }
  }

  // epilogue: C layout col = lane&15, row = (lane>>4)*4 + j  [measured m89]
  #pragma unroll
  for (int fm = 0; fm < 2; ++fm)
    #pragma unroll
    for (int fn = 0; fn < 4; ++fn) {
      const int mb = m0 + wr*32 + fm*16 + lg*4;
      const int e  = n0 + wc*64 + fn*16 + lr;
      if constexpr (MODE == 2) {
        int bb = mb >> 11, sb = mb & 2047, h = e >> 6, d = e & 63;
        u16x4 o4;
        #pragma unroll
        for (int j = 0; j < 4; ++j) o4[j] = f2bf(acc[fm][fn][j] + bias[e]*bscale);
        *reinterpret_cast<u16x4*>(
            reinterpret_cast<u16*>(outp) + (((size_t)(bb*HEADS+h))*DKV + d)*SEQ + sb) = o4;
      } else {
        #pragma unroll
        for (int j = 0; j < 4; ++j) {
          int m = mb + j;
          float val = acc[fm][fn][j] + bias[e]*bscale;
          if constexpr (MODE == 0) {
            int bb = m >> 11, s = m & 2047, h = e >> 6, d = e & 63;
            reinterpret_cast<u16*>(outp)[(((size_t)(bb*HEADS+h))*SEQ + s)*DKV + d] = f2bf(val);
          } else {
            reinterpret_cast<float*>(outp)[(size_t)m*EMB + e] = val;
          }
        }
      }
    }
}

// fused Q/K/V projections (x-cast fused: A operands are fp32)
__global__ __launch_bounds__(256) void qkv_k(
    const float* __restrict__ Xq, const float* __restrict__ Xk, const float* __restrict__ Xv,
    const u16* __restrict__ Wq, const u16* __restrict__ Wk, const u16* __restrict__ Wv,
    const float* __restrict__ bq, const float* __restrict__ bk, const float* __restrict__ bv,
    u16* __restrict__ Qh, u16* __restrict__ Kh, u16* __restrict__ Vh, float csc)
{
  __shared__ __align__(16) u16 At[64*64];      // 8 KB
  __shared__ __align__(16) u16 Bt[128*64];     // 16 KB
  const int m0 = blockIdx.x*64, n0 = blockIdx.y*128;
  const int z = blockIdx.z;
  if (z == 0)
    gemm_core<0,true>(Xq, Wq, bq, csc, csc, Qh, At, Bt, m0, n0);
  else if (z == 1)
    gemm_core<0,true>(Xk, Wk, bk, 1.f, 1.f, Kh, At, Bt, m0, n0);
  else
    gemm_core<2,true>(Xv, Wv, bv, 1.f, 1.f, Vh, At, Bt, m0, n0);
}

__global__ __launch_bounds__(256) void gemm_out_k(
    const u16* __restrict__ A, const u16* __restrict__ Bm,
    const float* __restrict__ bias, float* __restrict__ outp)
{
  __shared__ __align__(16) u16 At[64*64];
  __shared__ __align__(16) u16 Bt[128*64];
  gemm_core<1,false>(A, Bm, bias, 1.f, 1.f, outp, At, Bt, blockIdx.x*64, blockIdx.y*128);
}

// ---------------- flash attention: r7 structure + gload_lds K/V staging ----------------
// LDS-throughput-bound (r13 analysis: ~74% LDS-pipe util). gload_lds staging
// removes the 4 staging ds_writes/wave-tile (-20% LDS traffic) and the
// VMEM->VGPR round-trip. Write mapping (linear dest, source slot sg=sl^(row&7))
// reproduces exactly the phys/logical relation the r7 reads expect.
// Swapped QK^T, per-lane base-2 softmax, partial-lrun, defer-max THR=8,
// K/V double-buffered, ONE barrier/tile.
__global__ __launch_bounds__(256) void flash_attn_k(
    const u16* __restrict__ Q, const u16* __restrict__ K, const u16* __restrict__ VT,
    u16* __restrict__ av)
{
  __shared__ __align__(16) u16 Kt[2][64*64];     // [key][d]: phys p of row r = logical p^(r&7)
  __shared__ __align__(16) u16 Vt[2][64*64];     // [d][key]: same relation
  __shared__ __align__(16) u16 Pt[4][16*64];     // per-wave [q][k] swizzled

  const int t = threadIdx.x;
  const int w = t >> 6, lane = t & 63, lg = lane >> 4, lr = lane & 15;
  const int qb = blockIdx.x;       // 0..31
  const int bh = blockIdx.y;       // 0..23
  const u16* Qb = Q  + (size_t)bh*SEQ*DKV;
  const u16* Kb = K  + (size_t)bh*SEQ*DKV;
  const u16* Vb = VT + (size_t)bh*DKV*SEQ;

  const int qrow = qb*64 + w*16 + lr;
  u16x8 qf[2];
  qf[0] = *reinterpret_cast<const u16x8*>(Qb + (size_t)qrow*DKV + lg*8);
  qf[1] = *reinterpret_cast<const u16x8*>(Qb + (size_t)qrow*DKV + 32 + lg*8);

  f32x4 acc[4] = {};   // O^T: acc[fc][j] -> d = fc*16+lg*4+j, q = lr
  float mrun = -1e30f, lrun = 0.f;   // lrun = per-lane PARTIAL (16 keys/tile)

  auto STAGE = [&](int kt0, int bi) {
    #pragma unroll
    for (int c2 = 0; c2 < 2; ++c2) {
      int c = c2*256 + t;                 // 16B chunk 0..511
      int row = c >> 3, sl = c & 7;
      int sg = sl ^ (row & 7);            // pre-swizzled source slot
      gload16(Kb + (size_t)(kt0+row)*DKV + sg*8, &Kt[bi][c*8]);
    }
    #pragma unroll
    for (int c2 = 0; c2 < 2; ++c2) {
      int c = c2*256 + t;
      int row = c >> 3, sl = c & 7;       // row = d
      int sg = sl ^ (row & 7);
      gload16(Vb + (size_t)row*SEQ + kt0 + sg*8, &Vt[bi][c*8]);
    }
  };

  const int NT = SEQ/64;   // 32
  char* Pw = reinterpret_cast<char*>(&Pt[w][0]);

#define TILE(bi, kt)                                                          \
  do {                                                                        \
    if ((kt)+1 < NT) STAGE(((kt)+1)*64, (bi)^1);  /* async into other buf */  \
    f32x4 s[4];                                                               \
    __builtin_amdgcn_s_setprio(1);                                            \
    _Pragma("unroll")                                                         \
    for (int fc = 0; fc < 4; ++fc) {                                          \
      f32x4 z = {};                                                           \
      _Pragma("unroll")                                                       \
      for (int kk = 0; kk < 2; ++kk) {                                        \
        int r = fc*16 + lr;                                                   \
        int slot = (lg + 4*kk) ^ (r & 7);                                     \
        u16x8 kf = *reinterpret_cast<const u16x8*>(&Kt[bi][r*64 + slot*8]);   \
        z = mfma16(kf, qf[kk], z);                                            \
      }                                                                       \
      s[fc] = z;                                                              \
    }                                                                         \
    __builtin_amdgcn_s_setprio(0);                                            \
    float a0 = fmaxf(fmaxf(s[0][0], s[0][1]), s[0][2]);                       \
    float a1 = fmaxf(fmaxf(s[0][3], s[1][0]), s[1][1]);                       \
    float a2 = fmaxf(fmaxf(s[1][2], s[1][3]), s[2][0]);                       \
    float a3 = fmaxf(fmaxf(s[2][1], s[2][2]), s[2][3]);                       \
    float a4 = fmaxf(fmaxf(s[3][0], s[3][1]), s[3][2]);                       \
    float pmax = fmaxf(fmaxf(fmaxf(a0, a1), a2),                              \
                       fmaxf(fmaxf(a3, a4), s[3][3]));                        \
    if (__any(pmax > mrun + 8.f)) {   /* rare: full reduce + rescale */       \
      float pm = fmaxf(pmax, __shfl_xor(pmax, 16));                           \
      pm = fmaxf(pm, __shfl_xor(pm, 32));                                     \
      float mnew = fmaxf(mrun, pm);                                           \
      float corr = fexp2(mrun - mnew);                                        \
      mrun = mnew; lrun *= corr;                                              \
      _Pragma("unroll")                                                       \
      for (int fc = 0; fc < 4; ++fc)                                          \
        _Pragma("unroll")                                                     \
        for (int j = 0; j < 4; ++j)                                           \
          acc[fc][j] *= corr;                                                 \
    }                                                                         \
    float p[4][4], rs[4];                                                     \
    _Pragma("unroll")                                                         \
    for (int fc = 0; fc < 4; ++fc) {                                          \
      _Pragma("unroll")                                                       \
      for (int j = 0; j < 4; ++j) p[fc][j] = fexp2(s[fc][j] - mrun);          \
      rs[fc] = (p[fc][0] + p[fc][1]) + (p[fc][2] + p[fc][3]);                 \
    }                                                                         \
    lrun += (rs[0] + rs[1]) + (rs[2] + rs[3]);   /* partial: no shuffles */   \
    _Pragma("unroll")                                                         \
    for (int fc = 0; fc < 4; ++fc) {                                          \
      u16x4 q4;                                                               \
      _Pragma("unroll")                                                       \
      for (int j = 0; j < 4; ++j) q4[j] = f2bf(p[fc][j]);                     \
      *reinterpret_cast<u16x4*>(                                              \
          Pw + lr*128 + (((fc*4 + lg) ^ ((lr & 7) << 1))*8)) = q4;            \
    }                                                                         \
    asm volatile("s_waitcnt lgkmcnt(0)" ::: "memory");                        \
    __builtin_amdgcn_sched_barrier(0);                                        \
    __builtin_amdgcn_s_setprio(1);                                            \
    _Pragma("unroll")                                                         \
    for (int kk = 0; kk < 2; ++kk) {                                          \
      u16x8 pf = *reinterpret_cast<const u16x8*>(                             \
          Pw + lr*128 + (((kk*8 + lg*2) ^ ((lr & 7) << 1))*8));               \
      _Pragma("unroll")                                                       \
      for (int fc = 0; fc < 4; ++fc) {                                        \
        int rv = fc*16 + lr;                                                  \
        int slotv = (lg + 4*kk) ^ (rv & 7);                                   \
        u16x8 vf = *reinterpret_cast<const u16x8*>(&Vt[bi][rv*64 + slotv*8]); \
        acc[fc] = mfma16(vf, pf, acc[fc]);                                    \
      }                                                                       \
    }                                                                         \
    __builtin_amdgcn_s_setprio(0);                                            \
    __syncthreads();   /* drains gloads into buf^1 + all waves done with buf */\
  } while (0)

  STAGE(0, 0);
  __syncthreads();
  for (int kt = 0; kt < NT; kt += 2) {
    TILE(0, kt);
    TILE(1, kt+1);
  }
#undef TILE

  // epilogue: combine partial l across the 4 lg-lanes of each q-row, normalize
  float lt = lrun;
  lt += __shfl_xor(lt, 16);
  lt += __shfl_xor(lt, 32);
  const float inv = 1.0f / lt;

  const int b = bh / HEADS, h = bh % HEADS;
  #pragma unroll
  for (int fc = 0; fc < 4; ++fc) {
    u16x4 o4;
    #pragma unroll
    for (int j = 0; j < 4; ++j) o4[j] = f2bf(acc[fc][j] * inv);
    *reinterpret_cast<u16x4*>(
        av + ((size_t)(b*SEQ + qrow))*EMB + h*64 + fc*16 + lg*4) = o4;
  }
}

// ---------------- launcher: 4 kernels ----------------
extern "C" void kernel_launch(void* const* d_in, const int* in_sizes, int n_in,
                              void* d_out, int out_size, void* d_ws, size_t ws_size,
                              hipStream_t stream) {
  const float* xq_f = (const float*)d_in[0];
  const float* xk_f = (const float*)d_in[1];
  const float* xv_f = (const float*)d_in[2];
  const float* Wq = (const float*)d_in[3];
  const float* bq = (const float*)d_in[4];
  const float* Wk = (const float*)d_in[5];
  const float* bk = (const float*)d_in[6];
  const float* Wv = (const float*)d_in[7];
  const float* bv = (const float*)d_in[8];
  const float* Wo = (const float*)d_in[9];
  const float* bo = (const float*)d_in[10];

  const size_t NX = (size_t)NTOK*EMB;
  const size_t NW = (size_t)EMB*EMB;
  u16* Wc0 = (u16*)d_ws;
  u16* Wc1 = Wc0 + NW;
  u16* Wc2 = Wc1 + NW;
  u16* Wc3 = Wc2 + NW;
  u16* Qh  = Wc3 + NW;
  u16* Kh  = Qh + NX;
  u16* Vh  = Kh + NX;        // [B][H][DKV][SEQ] (V^T)
  u16* Xb  = Vh + NX;        // attn output bf16

  const float csc = 0.125f * 1.4426950408889634f;  // folded into Q A-tile + bq

  cast_w_k<<<dim3(4*EMB*EMB/8/256), dim3(256), 0, stream>>>(
      Wq, Wk, Wv, Wo, Wc0, Wc1, Wc2, Wc3);

  qkv_k<<<dim3(NTOK/64, EMB/128, 3), dim3(256), 0, stream>>>(
      xq_f, xk_f, xv_f, Wc0, Wc1, Wc2, bq, bk, bv, Qh, Kh, Vh, csc);

  flash_attn_k<<<dim3(SEQ/64, BATCH*HEADS), dim3(256), 0, stream>>>(Qh, Kh, Vh, Xb);

  gemm_out_k<<<dim3(NTOK/64, EMB/128), dim3(256), 0, stream>>>(Xb, Wc3, bo, (float*)d_out);
}

// Round 15
// 95.659 us; speedup vs baseline: 2.4110x; 1.0036x over previous
//
#include <hip/hip_runtime.h>
#include <hip/hip_bf16.h>

#define EMB 768
#define HEADS 12
#define DKV 64
#define BATCH 2
#define SEQ 2048
#define NTOK (BATCH*SEQ)   // 4096

typedef float f32x4 __attribute__((ext_vector_type(4)));
typedef unsigned short u16;
typedef u16 u16x8 __attribute__((ext_vector_type(8)));
typedef u16 u16x4 __attribute__((ext_vector_type(4)));
typedef __bf16 bf16x8 __attribute__((ext_vector_type(8)));

__device__ __forceinline__ u16 f2bf(float f) {
  return __builtin_bit_cast(u16, (__bf16)f);
}
__device__ __forceinline__ float fexp2(float x) {
#if __has_builtin(__builtin_amdgcn_exp2f)
  return __builtin_amdgcn_exp2f(x);
#else
  return exp2f(x);
#endif
}
__device__ __forceinline__ f32x4 mfma16(u16x8 a, u16x8 b, f32x4 c) {
  return __builtin_amdgcn_mfma_f32_16x16x32_bf16(
      __builtin_bit_cast(bf16x8, a), __builtin_bit_cast(bf16x8, b), c, 0, 0, 0);
}
// async global->LDS, 16B/lane; LDS dest = wave-uniform base + lane*16 (implicit)
__device__ __forceinline__ void gload16(const void* g, void* l) {
  __builtin_amdgcn_global_load_lds(
      (const __attribute__((address_space(1))) void*)g,
      (__attribute__((address_space(3))) void*)l, 16, 0, 0);
}

// ---------------- cast pass: 4 W's fp32 -> bf16 (x casts fused into qkv) ----------------
__global__ void cast_w_k(
    const float* __restrict__ w0, const float* __restrict__ w1,
    const float* __restrict__ w2, const float* __restrict__ w3,
    u16* __restrict__ W0, u16* __restrict__ W1, u16* __restrict__ W2, u16* __restrict__ W3)
{
  const int NW = EMB*EMB/8;    // 73728
  int i = blockIdx.x*256 + threadIdx.x;
  if (i >= 4*NW) return;
  int which = i / NW, off = i - which*NW;
  const float* s = which==0 ? w0 : which==1 ? w1 : which==2 ? w2 : w3;
  u16* d        = which==0 ? W0 : which==1 ? W1 : which==2 ? W2 : W3;
  float4 a = reinterpret_cast<const float4*>(s)[off*2];
  float4 b = reinterpret_cast<const float4*>(s)[off*2+1];
  u16x8 o;
  o[0]=f2bf(a.x); o[1]=f2bf(a.y); o[2]=f2bf(a.z); o[3]=f2bf(a.w);
  o[4]=f2bf(b.x); o[5]=f2bf(b.y); o[6]=f2bf(b.z); o[7]=f2bf(b.w);
  reinterpret_cast<u16x8*>(d)[off] = o;
}

// ---------------- GEMM core: 64x128 tile, DOUBLE-buffered, ONE barrier/step ----------------
// 4 waves (2x2), each wave 32x64 out. Step t: issue A_LOAD(t+1)(regs,fp32) +
// B_GLOAD(t+1 -> buf^1) EARLY, COMPUTE(buf), A_WRITE(buf^1), barrier (drains
// gloads that had the whole compute phase to land — removes the m233 stall of
// the old 2-barrier single-buffer loop). !AF32: A via gload too. LDS 48 KB.
// W staged via global_load_lds: LDS linear dest, pre-swizzled source (rule #21).
// MODE 0: bf16 head-split [B][H][S][DKV] (+bias*bscale).
// MODE 1: fp32 [M][EMB] (+bias). MODE 2: bf16 head-split transposed [B][H][DKV][SEQ].
template<int MODE, bool AF32>
__device__ __forceinline__ void gemm_core(
    const void* __restrict__ Ap, const u16* __restrict__ Bm,
    const float* __restrict__ bias, float ascale, float bscale,
    void* __restrict__ outp, u16* __restrict__ At, u16* __restrict__ Bt,
    int m0, int n0)
{
  const int t = threadIdx.x;
  const int w = t >> 6, lane = t & 63, lg = lane >> 4, lr = lane & 15;
  const int wr = w >> 1, wc = w & 1;
  const int lrow = lane >> 3, csl = lane & 7;   // gload chunk row/slot

  f32x4 acc[2][4] = {};
  f32x4 raf[2][2];   // AF32 staging regs

  auto A_LOAD = [&](int kb) {   // AF32: issue fp32 A loads early (T14)
    #pragma unroll
    for (int q2 = 0; q2 < 2; ++q2) {
      int c = q2*256 + t, row = c >> 3, sl = c & 7;
      const float* p = (const float*)Ap + (size_t)(m0+row)*EMB + kb + sl*8;
      raf[q2][0] = *reinterpret_cast<const f32x4*>(p);
      raf[q2][1] = *reinterpret_cast<const f32x4*>(p + 4);
    }
  };
  auto A_WRITE = [&](int bi) {  // AF32: cvt + swizzled ds_write into buf bi
    #pragma unroll
    for (int q2 = 0; q2 < 2; ++q2) {
      int c = q2*256 + t, row = c >> 3, sl = c & 7;
      u16x8 v;
      #pragma unroll
      for (int j = 0; j < 4; ++j) {
        v[j]   = f2bf(raf[q2][0][j] * ascale);
        v[4+j] = f2bf(raf[q2][1][j] * ascale);
      }
      *reinterpret_cast<u16x8*>(&At[bi*4096 + row*64 + ((sl ^ (row & 7))*8)]) = v;
    }
  };
  auto A_GLOAD = [&](int kb, int bi) {  // !AF32: A via global_load_lds (8 chunks)
    #pragma unroll
    for (int i = 0; i < 2; ++i) {
      int ci = w*2 + i;
      int row = ci*8 + lrow;
      int sg = csl ^ (row & 7);
      gload16((const u16*)Ap + (size_t)(m0+row)*EMB + kb + sg*8,
              &At[bi*4096 + ci*512]);
    }
  };
  auto B_GLOAD = [&](int kb, int bi) {  // B via global_load_lds (16 chunks)
    #pragma unroll
    for (int i = 0; i < 4; ++i) {
      int ci = w*4 + i;
      int row = ci*8 + lrow;
      int sg = csl ^ (row & 7);
      gload16(Bm + (size_t)(n0+row)*EMB + kb + sg*8, &Bt[bi*8192 + ci*512]);
    }
  };

  auto COMPUTE = [&](int bi) {
    u16x8 af[2][2], bf[4][2];
    #pragma unroll
    for (int fm = 0; fm < 2; ++fm)
      #pragma unroll
      for (int kk = 0; kk < 2; ++kk) {
        int r = wr*32 + fm*16 + lr;
        int p = (lg + 4*kk) ^ (r & 7);
        af[fm][kk] = *reinterpret_cast<const u16x8*>(&At[bi*4096 + r*64 + p*8]);
      }
    #pragma unroll
    for (int fn = 0; fn < 4; ++fn)
      #pragma unroll
      for (int kk = 0; kk < 2; ++kk) {
        int r = wc*64 + fn*16 + lr;
        int p = (lg + 4*kk) ^ (r & 7);
        bf[fn][kk] = *reinterpret_cast<const u16x8*>(&Bt[bi*8192 + r*64 + p*8]);
      }
    __builtin_amdgcn_s_setprio(1);
    #pragma unroll
    for (int fm = 0; fm < 2; ++fm)
      #pragma unroll
      for (int fn = 0; fn < 4; ++fn)
        #pragma unroll
        for (int kk = 0; kk < 2; ++kk)
          acc[fm][fn] = mfma16(af[fm][kk], bf[fn][kk], acc[fm][fn]);
    __builtin_amdgcn_s_setprio(0);
  };

  const int NSTEP = EMB/64;   // 12
  if constexpr (AF32) {
    A_LOAD(0);
    B_GLOAD(0, 0);
    A_WRITE(0);
    __syncthreads();                      // drains B gloads + A writes
    #pragma unroll
    for (int ts = 0; ts < NSTEP; ++ts) {
      if (ts+1 < NSTEP) {
        A_LOAD((ts+1)*64);                // fp32 regs land under COMPUTE
        B_GLOAD((ts+1)*64, (ts & 1) ^ 1); // async into other buf, under COMPUTE
      }
      COMPUTE(ts & 1);
      if (ts+1 < NSTEP) {
        A_WRITE((ts & 1) ^ 1);            // raf arrived during COMPUTE
        __syncthreads();                  // one barrier: gloads drained + writes visible
      }
    }
  } else {
    A_GLOAD(0, 0);
    B_GLOAD(0, 0);
    __syncthreads();
    #pragma unroll
    for (int ts = 0; ts < NSTEP; ++ts) {
      if (ts+1 < NSTEP) {
        A_GLOAD((ts+1)*64, (ts & 1) ^ 1);
        B_GLOAD((ts+1)*64, (ts & 1) ^ 1);
      }
      COMPUTE(ts & 1);
      if (ts+1 < NSTEP) __syncthreads();  // gload latency hidden under COMPUTE
    }
  }

  // epilogue: C layout col = lane&15, row = (lane>>4)*4 + j  [measured m89]
  #pragma unroll
  for (int fm = 0; fm < 2; ++fm)
    #pragma unroll
    for (int fn = 0; fn < 4; ++fn) {
      const int mb = m0 + wr*32 + fm*16 + lg*4;
      const int e  = n0 + wc*64 + fn*16 + lr;
      if constexpr (MODE == 2) {
        int bb = mb >> 11, sb = mb & 2047, h = e >> 6, d = e & 63;
        u16x4 o4;
        #pragma unroll
        for (int j = 0; j < 4; ++j) o4[j] = f2bf(acc[fm][fn][j] + bias[e]*bscale);
        *reinterpret_cast<u16x4*>(
            reinterpret_cast<u16*>(outp) + (((size_t)(bb*HEADS+h))*DKV + d)*SEQ + sb) = o4;
      } else {
        #pragma unroll
        for (int j = 0; j < 4; ++j) {
          int m = mb + j;
          float val = acc[fm][fn][j] + bias[e]*bscale;
          if constexpr (MODE == 0) {
            int bb = m >> 11, s = m & 2047, h = e >> 6, d = e & 63;
            reinterpret_cast<u16*>(outp)[(((size_t)(bb*HEADS+h))*SEQ + s)*DKV + d] = f2bf(val);
          } else {
            reinterpret_cast<float*>(outp)[(size_t)m*EMB + e] = val;
          }
        }
      }
    }
}

// fused Q/K/V projections (x-cast fused: A operands are fp32)
__global__ __launch_bounds__(256) void qkv_k(
    const float* __restrict__ Xq, const float* __restrict__ Xk, const float* __restrict__ Xv,
    const u16* __restrict__ Wq, const u16* __restrict__ Wk, const u16* __restrict__ Wv,
    const float* __restrict__ bq, const float* __restrict__ bk, const float* __restrict__ bv,
    u16* __restrict__ Qh, u16* __restrict__ Kh, u16* __restrict__ Vh, float csc)
{
  __shared__ __align__(16) u16 At[2*64*64];      // 16 KB
  __shared__ __align__(16) u16 Bt[2*128*64];     // 32 KB
  const int m0 = blockIdx.x*64, n0 = blockIdx.y*128;
  const int z = blockIdx.z;
  if (z == 0)
    gemm_core<0,true>(Xq, Wq, bq, csc, csc, Qh, At, Bt, m0, n0);
  else if (z == 1)
    gemm_core<0,true>(Xk, Wk, bk, 1.f, 1.f, Kh, At, Bt, m0, n0);
  else
    gemm_core<2,true>(Xv, Wv, bv, 1.f, 1.f, Vh, At, Bt, m0, n0);
}

__global__ __launch_bounds__(256) void gemm_out_k(
    const u16* __restrict__ A, const u16* __restrict__ Bm,
    const float* __restrict__ bias, float* __restrict__ outp)
{
  __shared__ __align__(16) u16 At[2*64*64];
  __shared__ __align__(16) u16 Bt[2*128*64];
  gemm_core<1,false>(A, Bm, bias, 1.f, 1.f, outp, At, Bt, blockIdx.x*64, blockIdx.y*128);
}

// ---------------- flash attention: r14 exact (52.6 us; frozen this round) ----------------
__global__ __launch_bounds__(256) void flash_attn_k(
    const u16* __restrict__ Q, const u16* __restrict__ K, const u16* __restrict__ VT,
    u16* __restrict__ av)
{
  __shared__ __align__(16) u16 Kt[2][64*64];     // [key][d]: phys p of row r = logical p^(r&7)
  __shared__ __align__(16) u16 Vt[2][64*64];     // [d][key]: same relation
  __shared__ __align__(16) u16 Pt[4][16*64];     // per-wave [q][k] swizzled

  const int t = threadIdx.x;
  const int w = t >> 6, lane = t & 63, lg = lane >> 4, lr = lane & 15;
  const int qb = blockIdx.x;       // 0..31
  const int bh = blockIdx.y;       // 0..23
  const u16* Qb = Q  + (size_t)bh*SEQ*DKV;
  const u16* Kb = K  + (size_t)bh*SEQ*DKV;
  const u16* Vb = VT + (size_t)bh*DKV*SEQ;

  const int qrow = qb*64 + w*16 + lr;
  u16x8 qf[2];
  qf[0] = *reinterpret_cast<const u16x8*>(Qb + (size_t)qrow*DKV + lg*8);
  qf[1] = *reinterpret_cast<const u16x8*>(Qb + (size_t)qrow*DKV + 32 + lg*8);

  f32x4 acc[4] = {};   // O^T: acc[fc][j] -> d = fc*16+lg*4+j, q = lr
  float mrun = -1e30f, lrun = 0.f;   // lrun = per-lane PARTIAL (16 keys/tile)

  auto STAGE = [&](int kt0, int bi) {
    #pragma unroll
    for (int c2 = 0; c2 < 2; ++c2) {
      int c = c2*256 + t;                 // 16B chunk 0..511
      int row = c >> 3, sl = c & 7;
      int sg = sl ^ (row & 7);            // pre-swizzled source slot
      gload16(Kb + (size_t)(kt0+row)*DKV + sg*8, &Kt[bi][c*8]);
    }
    #pragma unroll
    for (int c2 = 0; c2 < 2; ++c2) {
      int c = c2*256 + t;
      int row = c >> 3, sl = c & 7;       // row = d
      int sg = sl ^ (row & 7);
      gload16(Vb + (size_t)row*SEQ + kt0 + sg*8, &Vt[bi][c*8]);
    }
  };

  const int NT = SEQ/64;   // 32
  char* Pw = reinterpret_cast<char*>(&Pt[w][0]);

#define TILE(bi, kt)                                                          \
  do {                                                                        \
    if ((kt)+1 < NT) STAGE(((kt)+1)*64, (bi)^1);  /* async into other buf */  \
    f32x4 s[4];                                                               \
    __builtin_amdgcn_s_setprio(1);                                            \
    _Pragma("unroll")                                                         \
    for (int fc = 0; fc < 4; ++fc) {                                          \
      f32x4 z = {};                                                           \
      _Pragma("unroll")                                                       \
      for (int kk = 0; kk < 2; ++kk) {                                        \
        int r = fc*16 + lr;                                                   \
        int slot = (lg + 4*kk) ^ (r & 7);                                     \
        u16x8 kf = *reinterpret_cast<const u16x8*>(&Kt[bi][r*64 + slot*8]);   \
        z = mfma16(kf, qf[kk], z);                                            \
      }                                                                       \
      s[fc] = z;                                                              \
    }                                                                         \
    __builtin_amdgcn_s_setprio(0);                                            \
    float a0 = fmaxf(fmaxf(s[0][0], s[0][1]), s[0][2]);                       \
    float a1 = fmaxf(fmaxf(s[0][3], s[1][0]), s[1][1]);                       \
    float a2 = fmaxf(fmaxf(s[1][2], s[1][3]), s[2][0]);                       \
    float a3 = fmaxf(fmaxf(s[2][1], s[2][2]), s[2][3]);                       \
    float a4 = fmaxf(fmaxf(s[3][0], s[3][1]), s[3][2]);                       \
    float pmax = fmaxf(fmaxf(fmaxf(a0, a1), a2),                              \
                       fmaxf(fmaxf(a3, a4), s[3][3]));                        \
    if (__any(pmax > mrun + 8.f)) {   /* rare: full reduce + rescale */       \
      float pm = fmaxf(pmax, __shfl_xor(pmax, 16));                           \
      pm = fmaxf(pm, __shfl_xor(pm, 32));                                     \
      float mnew = fmaxf(mrun, pm);                                           \
      float corr = fexp2(mrun - mnew);                                        \
      mrun = mnew; lrun *= corr;                                              \
      _Pragma("unroll")                                                       \
      for (int fc = 0; fc < 4; ++fc)                                          \
        _Pragma("unroll")                                                     \
        for (int j = 0; j < 4; ++j)                                           \
          acc[fc][j] *= corr;                                                 \
    }                                                                         \
    float p[4][4], rs[4];                                                     \
    _Pragma("unroll")                                                         \
    for (int fc = 0; fc < 4; ++fc) {                                          \
      _Pragma("unroll")                                                       \
      for (int j = 0; j < 4; ++j) p[fc][j] = fexp2(s[fc][j] - mrun);          \
      rs[fc] = (p[fc][0] + p[fc][1]) + (p[fc][2] + p[fc][3]);                 \
    }                                                                         \
    lrun += (rs[0] + rs[1]) + (rs[2] + rs[3]);   /* partial: no shuffles */   \
    _Pragma("unroll")                                                         \
    for (int fc = 0; fc < 4; ++fc) {                                          \
      u16x4 q4;                                                               \
      _Pragma("unroll")                                                       \
      for (int j = 0; j < 4; ++j) q4[j] = f2bf(p[fc][j]);                     \
      *reinterpret_cast<u16x4*>(                                              \
          Pw + lr*128 + (((fc*4 + lg) ^ ((lr & 7) << 1))*8)) = q4;            \
    }                                                                         \
    asm volatile("s_waitcnt lgkmcnt(0)" ::: "memory");                        \
    __builtin_amdgcn_sched_barrier(0);                                        \
    __builtin_amdgcn_s_setprio(1);                                            \
    _Pragma("unroll")                                                         \
    for (int kk = 0; kk < 2; ++kk) {                                          \
      u16x8 pf = *reinterpret_cast<const u16x8*>(                             \
          Pw + lr*128 + (((kk*8 + lg*2) ^ ((lr & 7) << 1))*8));               \
      _Pragma("unroll")                                                       \
      for (int fc = 0; fc < 4; ++fc) {                                        \
        int rv = fc*16 + lr;                                                  \
        int slotv = (lg + 4*kk) ^ (rv & 7);                                   \
        u16x8 vf = *reinterpret_cast<const u16x8*>(&Vt[bi][rv*64 + slotv*8]); \
        acc[fc] = mfma16(vf, pf, acc[fc]);                                    \
      }                                                                       \
    }                                                                         \
    __builtin_amdgcn_s_setprio(0);                                            \
    __syncthreads();   /* drains gloads into buf^1 + all waves done with buf */\
  } while (0)

  STAGE(0, 0);
  __syncthreads();
  for (int kt = 0; kt < NT; kt += 2) {
    TILE(0, kt);
    TILE(1, kt+1);
  }
#undef TILE

  // epilogue: combine partial l across the 4 lg-lanes of each q-row, normalize
  float lt = lrun;
  lt += __shfl_xor(lt, 16);
  lt += __shfl_xor(lt, 32);
  const float inv = 1.0f / lt;

  const int b = bh / HEADS, h = bh % HEADS;
  #pragma unroll
  for (int fc = 0; fc < 4; ++fc) {
    u16x4 o4;
    #pragma unroll
    for (int j = 0; j < 4; ++j) o4[j] = f2bf(acc[fc][j] * inv);
    *reinterpret_cast<u16x4*>(
        av + ((size_t)(b*SEQ + qrow))*EMB + h*64 + fc*16 + lg*4) = o4;
  }
}

// ---------------- launcher: 4 kernels ----------------
extern "C" void kernel_launch(void* const* d_in, const int* in_sizes, int n_in,
                              void* d_out, int out_size, void* d_ws, size_t ws_size,
                              hipStream_t stream) {
  const float* xq_f = (const float*)d_in[0];
  const float* xk_f = (const float*)d_in[1];
  const float* xv_f = (const float*)d_in[2];
  const float* Wq = (const float*)d_in[3];
  const float* bq = (const float*)d_in[4];
  const float* Wk = (const float*)d_in[5];
  const float* bk = (const float*)d_in[6];
  const float* Wv = (const float*)d_in[7];
  const float* bv = (const float*)d_in[8];
  const float* Wo = (const float*)d_in[9];
  const float* bo = (const float*)d_in[10];

  const size_t NX = (size_t)NTOK*EMB;
  const size_t NW = (size_t)EMB*EMB;
  u16* Wc0 = (u16*)d_ws;
  u16* Wc1 = Wc0 + NW;
  u16* Wc2 = Wc1 + NW;
  u16* Wc3 = Wc2 + NW;
  u16* Qh  = Wc3 + NW;
  u16* Kh  = Qh + NX;
  u16* Vh  = Kh + NX;        // [B][H][DKV][SEQ] (V^T)
  u16* Xb  = Vh + NX;        // attn output bf16

  const float csc = 0.125f * 1.4426950408889634f;  // folded into Q A-tile + bq

  cast_w_k<<<dim3(4*EMB*EMB/8/256), dim3(256), 0, stream>>>(
      Wq, Wk, Wv, Wo, Wc0, Wc1, Wc2, Wc3);

  qkv_k<<<dim3(NTOK/64, EMB/128, 3), dim3(256), 0, stream>>>(
      xq_f, xk_f, xv_f, Wc0, Wc1, Wc2, bq, bk, bv, Qh, Kh, Vh, csc);

  flash_attn_k<<<dim3(SEQ/64, BATCH*HEADS), dim3(256), 0, stream>>>(Qh, Kh, Vh, Xb);

  gemm_out_k<<<dim3(NTOK/64, EMB/128), dim3(256), 0, stream>>>(Xb, Wc3, bo, (float*)d_out);
}